// Round 15
// baseline (482.651 us; speedup 1.0000x reference)
//
#include <hip/hip_runtime.h>
#include <hip/hip_fp16.h>
#include <math.h>
#include <type_traits>

#define DEVI __device__ __forceinline__

typedef __attribute__((ext_vector_type(8))) short bf16x8;
typedef __attribute__((ext_vector_type(4))) float f32x4;
typedef __attribute__((ext_vector_type(4))) unsigned int u32x4;
typedef unsigned short ushort_t;

DEVI unsigned int pack_bf16(float a, float b) {
  unsigned int ua = __float_as_uint(a), ub = __float_as_uint(b);
  ua = (ua + 0x7FFFu + ((ua >> 16) & 1u)) >> 16;   // RNE
  ub = (ub + 0x7FFFu + ((ub >> 16) & 1u)) >> 16;
  return ua | (ub << 16);
}

DEVI ushort_t rnd_bf16(float a) {
  unsigned int ua = __float_as_uint(a);
  return (ushort_t)((ua + 0x7FFFu + ((ua >> 16) & 1u)) >> 16);
}

DEVI bf16x8 cvt_bf16x8(f32x4 lo, f32x4 hi) {
  unsigned int r0, r1, r2, r3;
  asm("v_cvt_pk_bf16_f32 %0, %1, %2" : "=v"(r0) : "v"(lo[0]), "v"(lo[1]));
  asm("v_cvt_pk_bf16_f32 %0, %1, %2" : "=v"(r1) : "v"(lo[2]), "v"(lo[3]));
  asm("v_cvt_pk_bf16_f32 %0, %1, %2" : "=v"(r2) : "v"(hi[0]), "v"(hi[1]));
  asm("v_cvt_pk_bf16_f32 %0, %1, %2" : "=v"(r3) : "v"(hi[2]), "v"(hi[3]));
  union { u32x4 u; bf16x8 v; } x;
  x.u = u32x4{r0, r1, r2, r3};
  return x.v;
}

// =======================================================================
// bgemmA32: C[M,N] = A_fp32[M,K] * B_bf16[N,K]^T, 4-phase counted-vmcnt
// pipeline, BM=128, BN=256, BK=64, 8 waves. LDS 128KB dbuf (1 block/CU —
// only use when grid <= 256 and K large; r13 post-mortem). A converted
// bf16 at frag read (v_cvt_pk RNE). Peeled reg-staged 32-tail on last z.
// =======================================================================
template<int SPLITZ, bool TAIL, typename OutT>
__global__ __launch_bounds__(512, 1) void bgemmA32(
    const float* __restrict__ A, const ushort_t* __restrict__ B,
    OutT* __restrict__ C, int M, int N, int K, int nbn, int nbm)
{
  __shared__ __align__(16) char L[131072];  // A:[0,64K) B:[64K,128K)
  const int tid = threadIdx.x, lane = tid & 63, wv = tid >> 6;

  const int nwg = gridDim.x;
  const int hw = blockIdx.x;
  const int q = nwg >> 3, r = nwg & 7;
  const int xcd = hw & 7, pos = hw >> 3;
  const int lid = (xcd < r ? xcd * (q + 1) : r * (q + 1) + (xcd - r) * q) + pos;
  const int bn = lid % nbn;
  const int t2 = lid / nbn;
  const int bm = t2 % nbm;
  const int z  = t2 / nbm;

  const int ksteps = K >> 6;
  const int szk = (ksteps + SPLITZ - 1) / SPLITZ;
  const int kbBeg = z * szk;
  const int kbEnd = min(ksteps, kbBeg + szk);

  const int wm = wv >> 2, wn = wv & 3;
  const int lrow = lane & 15, kg = lane >> 4;

  f32x4 acc[4][4];
#pragma unroll
  for (int i = 0; i < 4; ++i)
#pragma unroll
    for (int j = 0; j < 4; ++j) acc[i][j] = f32x4{0.f, 0.f, 0.f, 0.f};

  const int alr = lane >> 3, ag32 = (lane & 7) >> 1;
  const float* aS[2];
#pragma unroll
  for (int j = 0; j < 2; ++j) {
    const int lr = (wv * 2 + j) * 8 + alr;
    const int swz = (lr ^ (lr >> 2)) & 3;
    const int colf = ((ag32 ^ swz) << 3) + (lane & 1) * 4;
    aS[j] = A + (size_t)min(bm * 128 + lr, M - 1) * (size_t)K + colf;
  }
  const int blr = lane >> 2, bgq = lane & 3;
  const ushort_t* bS[2];
#pragma unroll
  for (int j = 0; j < 2; ++j) {
    const int lr = (wv * 2 + j) * 16 + blr;
    const int swz = (lr ^ (lr >> 2)) & 3;
    bS[j] = B + (size_t)min(bn * 256 + lr, N - 1) * (size_t)K + ((bgq ^ swz) << 3);
  }

  int offA[4], offB[4];
#pragma unroll
  for (int i = 0; i < 4; ++i) {
    const int ra = wm * 64 + i * 16 + lrow;
    offA[i] = ra * 128 + ((kg ^ ((ra ^ (ra >> 2)) & 3)) << 5);
  }
#pragma unroll
  for (int j = 0; j < 4; ++j) {
    const int rb = wn * 64 + j * 16 + lrow;
    offB[j] = rb * 64 + ((kg ^ ((rb ^ (rb >> 2)) & 3)) << 4);
  }

#define GA_STGA(h, k0v) do {                                                  \
    _Pragma("unroll")                                                         \
    for (int j_ = 0; j_ < 2; ++j_)                                            \
      __builtin_amdgcn_global_load_lds(                                       \
          (const __attribute__((address_space(1))) void*)(aS[j_] + (k0v) + (h) * 32), \
          (__attribute__((address_space(3))) void*)                           \
              (L + (s ^ 1) * 32768 + (h) * 16384 + (wv * 2 + j_) * 1024),     \
          16, 0, 0);                                                          \
  } while (0)
#define GA_STGB(h, k0v) do {                                                  \
    _Pragma("unroll")                                                         \
    for (int j_ = 0; j_ < 2; ++j_)                                            \
      __builtin_amdgcn_global_load_lds(                                       \
          (const __attribute__((address_space(1))) void*)(bS[j_] + (k0v) + (h) * 32), \
          (__attribute__((address_space(3))) void*)                           \
              (L + 65536 + (s ^ 1) * 32768 + (h) * 16384 + (wv * 2 + j_) * 1024), \
          16, 0, 0);                                                          \
  } while (0)
#define GA_RDB(h) do {                                                        \
    _Pragma("unroll")                                                         \
    for (int j_ = 0; j_ < 4; ++j_)                                            \
      bfv[j_] = *(const bf16x8*)(L + 65536 + s * 32768 + (h) * 16384 + offB[j_]); \
  } while (0)
#define GA_RDA(h, rg) do {                                                    \
    _Pragma("unroll")                                                         \
    for (int i_ = 0; i_ < 2; ++i_) {                                          \
      const char* pa_ = L + s * 32768 + (h) * 16384 + offA[(rg) * 2 + i_];    \
      af[i_] = cvt_bf16x8(*(const f32x4*)pa_, *(const f32x4*)(pa_ + 16));     \
    }                                                                         \
  } while (0)
#define GA_MM(rg) do {                                                        \
    _Pragma("unroll")                                                         \
    for (int i_ = 0; i_ < 2; ++i_)                                            \
      _Pragma("unroll")                                                       \
      for (int j_ = 0; j_ < 4; ++j_)                                          \
        acc[(rg) * 2 + i_][j_] = __builtin_amdgcn_mfma_f32_16x16x32_bf16(     \
            af[i_], bfv[j_], acc[(rg) * 2 + i_][j_], 0, 0, 0);                \
  } while (0)
#define GA_BAR asm volatile("s_barrier" ::: "memory")

  {
    int s = 1;
    const int k0 = kbBeg << 6;
    GA_STGA(0, k0); GA_STGB(0, k0); GA_STGA(1, k0); GA_STGB(1, k0);
  }
  asm volatile("s_waitcnt vmcnt(4)" ::: "memory");
  GA_BAR;

  int s = 0;
  for (int t = kbBeg; t < kbEnd; ++t) {
    const bool more = (t + 1 < kbEnd);
    const int k0n = (t + 1) << 6;
    bf16x8 af[2], bfv[4];
    GA_RDB(0); GA_RDA(0, 0);
    if (more) GA_STGA(0, k0n);
    GA_BAR;
    __builtin_amdgcn_s_setprio(1); GA_MM(0); __builtin_amdgcn_s_setprio(0);
    GA_BAR;
    GA_RDA(0, 1);
    if (more) GA_STGB(0, k0n);
    GA_BAR;
    __builtin_amdgcn_s_setprio(1); GA_MM(1); __builtin_amdgcn_s_setprio(0);
    if (more) asm volatile("s_waitcnt vmcnt(4)" ::: "memory");
    else      asm volatile("s_waitcnt vmcnt(0)" ::: "memory");
    GA_BAR;
    GA_RDB(1); GA_RDA(1, 0);
    if (more) GA_STGA(1, k0n);
    GA_BAR;
    __builtin_amdgcn_s_setprio(1); GA_MM(0); __builtin_amdgcn_s_setprio(0);
    GA_BAR;
    GA_RDA(1, 1);
    if (more) GA_STGB(1, k0n);
    GA_BAR;
    __builtin_amdgcn_s_setprio(1); GA_MM(1); __builtin_amdgcn_s_setprio(0);
    if (more) asm volatile("s_waitcnt vmcnt(4)" ::: "memory");
    GA_BAR;
    s ^= 1;
  }

  if (TAIL && z == SPLITZ - 1 && (K & 63)) {
    const int k0t = ksteps << 6;
    bf16x8 af[2], bfv[4];
#pragma unroll
    for (int j = 0; j < 2; ++j) {
      const float4 av = *(const float4*)(aS[j] + k0t);
      *(float4*)(L + s * 32768 + (wv * 2 + j) * 1024 + lane * 16) = av;
      const u32x4 bv = *(const u32x4*)(bS[j] + k0t);
      *(u32x4*)(L + 65536 + s * 32768 + (wv * 2 + j) * 1024 + lane * 16) = bv;
    }
    __syncthreads();
    GA_RDB(0);
    GA_RDA(0, 0); GA_MM(0);
    GA_RDA(0, 1); GA_MM(1);
  }
#undef GA_STGA
#undef GA_STGB
#undef GA_RDB
#undef GA_RDA
#undef GA_MM
#undef GA_BAR

  const size_t zoff = (SPLITZ > 1) ? (size_t)z * (size_t)M * (size_t)N : 0;
#pragma unroll
  for (int i = 0; i < 4; ++i) {
#pragma unroll
    for (int j = 0; j < 4; ++j) {
      const int col = bn * 256 + wn * 64 + j * 16 + lrow;
      if (col >= N) continue;
      const int row0 = bm * 128 + wm * 64 + i * 16 + kg * 4;
#pragma unroll
      for (int rr = 0; rr < 4; ++rr) {
        const int gr = row0 + rr;
        if (gr < M) {
          const float v = acc[i][j][rr];
          if constexpr (std::is_same<OutT, __half>::value)
            C[zoff + (size_t)gr * (size_t)N + col] = __float2half(v);
          else
            C[zoff + (size_t)gr * (size_t)N + col] = v;
        }
      }
    }
  }
}

// =======================================================================
// bgemm256: all-bf16 256x256 4-phase pipeline. K%64==0. No epilogue
// side-effects (r12 lesson: divergent atomics in wide epilogue = 11x).
// =======================================================================
template<int SPLITZ, typename OutT>
__global__ __launch_bounds__(512, 1) void bgemm256(
    const ushort_t* __restrict__ A, const ushort_t* __restrict__ B,
    OutT* __restrict__ C, int M, int N, int K, int nbn, int nbm)
{
  __shared__ __align__(16) char L[131072];
  const int tid = threadIdx.x, lane = tid & 63, wv = tid >> 6;

  const int nwg = gridDim.x;
  const int hw = blockIdx.x;
  const int q = nwg >> 3, r = nwg & 7;
  const int xcd = hw & 7, pos = hw >> 3;
  const int lid = (xcd < r ? xcd * (q + 1) : r * (q + 1) + (xcd - r) * q) + pos;
  const int bn = lid % nbn;
  const int t2 = lid / nbn;
  const int bm = t2 % nbm;
  const int z  = t2 / nbm;

  const int ksteps = K >> 6;
  int kbBeg = 0, kbEnd = ksteps;
  if (SPLITZ > 1) {
    const int sz = (ksteps + SPLITZ - 1) / SPLITZ;
    kbBeg = z * sz;
    kbEnd = min(ksteps, kbBeg + sz);
  }

  const int wm = wv >> 2, wn = wv & 3;
  const int lrow = lane & 15, kg = lane >> 4;

  f32x4 acc[8][4];
#pragma unroll
  for (int i = 0; i < 8; ++i)
#pragma unroll
    for (int j = 0; j < 4; ++j) acc[i][j] = f32x4{0.f, 0.f, 0.f, 0.f};

  const int sr = lane >> 2, sq = lane & 3;
  const ushort_t* aS[2];
  const ushort_t* bS[2];
#pragma unroll
  for (int j = 0; j < 2; ++j) {
    const int lr = (wv * 2 + j) * 16 + sr;
    const int swz = (lr ^ (lr >> 2)) & 3;
    aS[j] = A + (size_t)min(bm * 256 + lr, M - 1) * (size_t)K + ((sq ^ swz) << 3);
    bS[j] = B + (size_t)min(bn * 256 + lr, N - 1) * (size_t)K + ((sq ^ swz) << 3);
  }

  int offA[8], offB[4];
#pragma unroll
  for (int i = 0; i < 8; ++i) {
    const int ra = wm * 128 + i * 16 + lrow;
    offA[i] = ra * 64 + (((kg ^ ((ra ^ (ra >> 2)) & 3))) << 4);
  }
#pragma unroll
  for (int j = 0; j < 4; ++j) {
    const int rb = wn * 64 + j * 16 + lrow;
    offB[j] = rb * 64 + (((kg ^ ((rb ^ (rb >> 2)) & 3))) << 4);
  }

#define G256_STG(isB, h, k0v) do {                                            \
    _Pragma("unroll")                                                         \
    for (int j_ = 0; j_ < 2; ++j_)                                            \
      __builtin_amdgcn_global_load_lds(                                       \
          (const __attribute__((address_space(1))) void*)                     \
              (((isB) ? bS : aS)[j_] + (k0v) + (h) * 32),                     \
          (__attribute__((address_space(3))) void*)                           \
              (L + (isB) * 65536 + (s ^ 1) * 32768 + (h) * 16384 +            \
               (wv * 2 + j_) * 1024), 16, 0, 0);                              \
  } while (0)
#define G256_RDA(h, rg) do {                                                  \
    _Pragma("unroll")                                                         \
    for (int i_ = 0; i_ < 4; ++i_)                                            \
      af[i_] = *(const bf16x8*)(L + s * 32768 + (h) * 16384 +                 \
                                offA[(rg) * 4 + i_]);                         \
  } while (0)
#define G256_RDB(h) do {                                                      \
    _Pragma("unroll")                                                         \
    for (int j_ = 0; j_ < 4; ++j_)                                            \
      bfv[j_] = *(const bf16x8*)(L + 65536 + s * 32768 + (h) * 16384 +        \
                                 offB[j_]);                                   \
  } while (0)
#define G256_MM(rg) do {                                                      \
    _Pragma("unroll")                                                         \
    for (int i_ = 0; i_ < 4; ++i_)                                            \
      _Pragma("unroll")                                                       \
      for (int j_ = 0; j_ < 4; ++j_)                                          \
        acc[(rg) * 4 + i_][j_] = __builtin_amdgcn_mfma_f32_16x16x32_bf16(     \
            af[i_], bfv[j_], acc[(rg) * 4 + i_][j_], 0, 0, 0);                \
  } while (0)
#define G256_BAR asm volatile("s_barrier" ::: "memory")

  {
    int s = 1;
    const int k0 = kbBeg << 6;
    G256_STG(0, 0, k0);
    G256_STG(1, 0, k0);
    G256_STG(0, 1, k0);
    G256_STG(1, 1, k0);
  }
  asm volatile("s_waitcnt vmcnt(4)" ::: "memory");
  G256_BAR;

  int s = 0;
  for (int t = kbBeg; t < kbEnd; ++t) {
    const bool more = (t + 1 < kbEnd);
    const int k0n = (t + 1) << 6;
    bf16x8 af[4], bfv[4];
    G256_RDB(0);
    G256_RDA(0, 0);
    if (more) G256_STG(0, 0, k0n);
    G256_BAR;
    __builtin_amdgcn_s_setprio(1); G256_MM(0); __builtin_amdgcn_s_setprio(0);
    G256_BAR;
    G256_RDA(0, 1);
    if (more) G256_STG(1, 0, k0n);
    G256_BAR;
    __builtin_amdgcn_s_setprio(1); G256_MM(1); __builtin_amdgcn_s_setprio(0);
    if (more) asm volatile("s_waitcnt vmcnt(4)" ::: "memory");
    else      asm volatile("s_waitcnt vmcnt(0)" ::: "memory");
    G256_BAR;
    G256_RDB(1);
    G256_RDA(1, 0);
    if (more) G256_STG(0, 1, k0n);
    G256_BAR;
    __builtin_amdgcn_s_setprio(1); G256_MM(0); __builtin_amdgcn_s_setprio(0);
    G256_BAR;
    G256_RDA(1, 1);
    if (more) G256_STG(1, 1, k0n);
    G256_BAR;
    __builtin_amdgcn_s_setprio(1); G256_MM(1); __builtin_amdgcn_s_setprio(0);
    if (more) asm volatile("s_waitcnt vmcnt(4)" ::: "memory");
    G256_BAR;
    s ^= 1;
  }
#undef G256_STG
#undef G256_RDA
#undef G256_RDB
#undef G256_MM
#undef G256_BAR

  const size_t zoff = (SPLITZ > 1) ? (size_t)z * (size_t)M * (size_t)N : 0;
#pragma unroll
  for (int i = 0; i < 8; ++i) {
#pragma unroll
    for (int j = 0; j < 4; ++j) {
      const int col = bn * 256 + wn * 64 + j * 16 + lrow;
      if (col >= N) continue;
      const int row0 = bm * 256 + wm * 128 + i * 16 + kg * 4;
#pragma unroll
      for (int rr = 0; rr < 4; ++rr) {
        const int gr = row0 + rr;
        if (gr < M) {
          const float v = acc[i][j][rr];
          if constexpr (std::is_same<OutT, __half>::value)
            C[zoff + (size_t)gr * (size_t)N + col] = __float2half(v);
          else
            C[zoff + (size_t)gr * (size_t)N + col] = v;
        }
      }
    }
  }
}

// =======================================================================
// old bgemm (e-GEMM / GEMM4): 128x256, BK=64, 8 waves, single-buf.
// fp32-A: 2 blocks/CU; bf16-A: 3 blocks/CU. Best for short-K / big grids.
// =======================================================================
template<typename AT, int SPLITZ, bool BIAS, typename OutT>
__global__ __launch_bounds__(512, sizeof(AT) == 2 ? 3 : 2) void bgemm(
    const AT* __restrict__ A, const ushort_t* __restrict__ B0,
    const float* __restrict__ bias0, OutT* __restrict__ C,
    int M, int N, int K, int nbn, int nbm)
{
  constexpr bool AB16 = (sizeof(AT) == 2);
  __shared__ __align__(16) char AsB[AB16 ? 16384 : 32768];
  __shared__ __align__(16) char BsB[32768];
  const int tid = threadIdx.x, lane = tid & 63, wv = tid >> 6;

  const int nwg = gridDim.x;
  const int hw = blockIdx.x;
  const int q = nwg >> 3, r = nwg & 7;
  const int xcd = hw & 7, pos = hw >> 3;
  const int lid = (xcd < r ? xcd * (q + 1) : r * (q + 1) + (xcd - r) * q) + pos;
  const int bn = lid % nbn;
  const int t2 = lid / nbn;
  const int bm = t2 % nbm;
  const int z  = t2 / nbm;

  const ushort_t* B  = B0;
  const float* bias  = bias0;

  const int ksteps = (K + 63) >> 6;
  int kbBeg = 0, kbEnd = ksteps;
  if (SPLITZ > 1) {
    const int sz = (ksteps + SPLITZ - 1) / SPLITZ;
    kbBeg = z * sz;
    kbEnd = min(ksteps, kbBeg + sz);
  }

  const int wr = (wv >> 2) * 64;
  const int wc = (wv & 3) * 64;
  const int lrow = lane & 15, kg = lane >> 4;

  f32x4 acc[4][4];
#pragma unroll
  for (int i = 0; i < 4; ++i)
#pragma unroll
    for (int j = 0; j < 4; ++j) acc[i][j] = f32x4{0.f, 0.f, 0.f, 0.f};

  const AT* aSrc[4];
  if constexpr (AB16) {
    const int r0 = lane >> 3;
    const int ce = ((lane & 7) ^ r0) << 3;
#pragma unroll
    for (int j = 0; j < 2; ++j) {
      const int row = wv * 16 + j * 8 + r0;
      aSrc[j] = A + (size_t)min(bm * 128 + row, M - 1) * (size_t)K + ce;
    }
  } else {
    const int r0 = lane >> 4;
#pragma unroll
    for (int j = 0; j < 4; ++j) {
      const int row = wv * 16 + j * 4 + r0;
      const int ca = ((lane & 15) << 2) ^ ((row & 7) << 3);
      aSrc[j] = A + (size_t)min(bm * 128 + row, M - 1) * (size_t)K + ca;
    }
  }
  const int rB0 = lane >> 3;
  const int colB = ((lane & 7) ^ rB0) << 3;
  const ushort_t* bSrc[4];
#pragma unroll
  for (int j = 0; j < 4; ++j) {
    const int row = wv * 32 + j * 8 + rB0;
    bSrc[j] = B + (size_t)min(bn * 256 + row, N - 1) * (size_t)K + colB;
  }

  for (int kb = kbBeg; kb < kbEnd; ++kb) {
    const int k0 = kb << 6;
    if constexpr (AB16) {
#pragma unroll
      for (int j = 0; j < 2; ++j)
        __builtin_amdgcn_global_load_lds(
            (const __attribute__((address_space(1))) void*)(aSrc[j] + k0),
            (__attribute__((address_space(3))) void*)(AsB + (wv * 2 + j) * 1024),
            16, 0, 0);
    } else {
#pragma unroll
      for (int j = 0; j < 4; ++j)
        __builtin_amdgcn_global_load_lds(
            (const __attribute__((address_space(1))) void*)(aSrc[j] + k0),
            (__attribute__((address_space(3))) void*)(AsB + (wv * 4 + j) * 1024),
            16, 0, 0);
    }
#pragma unroll
    for (int j = 0; j < 4; ++j)
      __builtin_amdgcn_global_load_lds(
          (const __attribute__((address_space(1))) void*)(bSrc[j] + k0),
          (__attribute__((address_space(3))) void*)(BsB + (wv * 4 + j) * 1024),
          16, 0, 0);
    __syncthreads();
#pragma unroll
    for (int kk = 0; kk < 2; ++kk) {
      bf16x8 af[4], bfr[4];
#pragma unroll
      for (int i = 0; i < 4; ++i) {
        const int ra = wr + i * 16 + lrow;
        if constexpr (AB16) {
          af[i] = *(const bf16x8*)(AsB + ra * 128 + ((((kk << 2) + kg) ^ (ra & 7)) << 4));
        } else {
          const char* pa = AsB + ra * 256 + ((kk * 128 + (kg << 5)) ^ ((ra & 7) << 5));
          af[i] = cvt_bf16x8(*(const f32x4*)pa, *(const f32x4*)(pa + 16));
        }
        const int rb = wc + i * 16 + lrow;
        bfr[i] = *(const bf16x8*)(BsB + rb * 128 + ((((kk << 2) + kg) ^ (rb & 7)) << 4));
      }
#pragma unroll
      for (int i = 0; i < 4; ++i)
#pragma unroll
        for (int j = 0; j < 4; ++j)
          acc[i][j] = __builtin_amdgcn_mfma_f32_16x16x32_bf16(af[i], bfr[j], acc[i][j], 0, 0, 0);
    }
    __syncthreads();
  }

  const size_t zoff = (SPLITZ > 1) ? (size_t)z * (size_t)M * (size_t)N : 0;
#pragma unroll
  for (int i = 0; i < 4; ++i) {
#pragma unroll
    for (int j = 0; j < 4; ++j) {
      const int col = bn * 256 + wc + j * 16 + lrow;
      if (col >= N) continue;
      const int row0 = bm * 128 + wr + i * 16 + kg * 4;
      float bv = 0.f;
      if (BIAS) bv = bias[col];
#pragma unroll
      for (int rr = 0; rr < 4; ++rr) {
        const int gr = row0 + rr;
        if (gr < M) {
          const float v = acc[i][j][rr] + bv;
          if constexpr (std::is_same<OutT, __half>::value)
            C[zoff + (size_t)gr * (size_t)N + col] = __float2half(v);
          else
            C[zoff + (size_t)gr * (size_t)N + col] = v;
        }
      }
    }
  }
}

// =======================================================================
// bgemm_film: gamma = ctxb@WgT+bg, beta = ctxb@WbT+bb, then
// hcb = bf16((1+gamma)*hx + beta). M=4096 N=512 K=512.
// =======================================================================
__global__ __launch_bounds__(512, 2) void bgemm_film(
    const ushort_t* __restrict__ A, const ushort_t* __restrict__ BG,
    const ushort_t* __restrict__ BB, const float* __restrict__ bg,
    const float* __restrict__ bb, const float* __restrict__ hx,
    ushort_t* __restrict__ hcb)
{
  constexpr int M = 4096, N = 512, K = 512;
  __shared__ __align__(16) char AsB[16384];
  __shared__ __align__(16) char BsB[65536];   // G:[0,32K) B:[32K,64K)
  const int tid = threadIdx.x, lane = tid & 63, wv = tid >> 6;

  const int nwg = gridDim.x;
  const int hw = blockIdx.x;
  const int q = nwg >> 3, r = nwg & 7;
  const int xcd = hw & 7, pos = hw >> 3;
  const int lid = (xcd < r ? xcd * (q + 1) : r * (q + 1) + (xcd - r) * q) + pos;
  const int bn = lid % 2;
  const int bm = lid / 2;

  const int wr = (wv >> 2) * 64;
  const int wc = (wv & 3) * 64;
  const int lrow = lane & 15, kg = lane >> 4;

  f32x4 accG[4][4], accB[4][4];
#pragma unroll
  for (int i = 0; i < 4; ++i)
#pragma unroll
    for (int j = 0; j < 4; ++j) {
      accG[i][j] = f32x4{0.f, 0.f, 0.f, 0.f};
      accB[i][j] = f32x4{0.f, 0.f, 0.f, 0.f};
    }

  const int r0 = lane >> 3;
  const int ce = ((lane & 7) ^ r0) << 3;
  const ushort_t* aSrc[2];
#pragma unroll
  for (int j = 0; j < 2; ++j) {
    const int row = wv * 16 + j * 8 + r0;
    aSrc[j] = A + (size_t)(bm * 128 + row) * (size_t)K + ce;
  }
  const ushort_t* gSrc[4];
  const ushort_t* bSrc[4];
#pragma unroll
  for (int j = 0; j < 4; ++j) {
    const int row = wv * 32 + j * 8 + r0;
    gSrc[j] = BG + (size_t)(bn * 256 + row) * (size_t)K + ce;
    bSrc[j] = BB + (size_t)(bn * 256 + row) * (size_t)K + ce;
  }

  for (int kb = 0; kb < K / 64; ++kb) {
    const int k0 = kb << 6;
#pragma unroll
    for (int j = 0; j < 2; ++j)
      __builtin_amdgcn_global_load_lds(
          (const __attribute__((address_space(1))) void*)(aSrc[j] + k0),
          (__attribute__((address_space(3))) void*)(AsB + (wv * 2 + j) * 1024),
          16, 0, 0);
#pragma unroll
    for (int j = 0; j < 4; ++j) {
      __builtin_amdgcn_global_load_lds(
          (const __attribute__((address_space(1))) void*)(gSrc[j] + k0),
          (__attribute__((address_space(3))) void*)(BsB + (wv * 4 + j) * 1024),
          16, 0, 0);
      __builtin_amdgcn_global_load_lds(
          (const __attribute__((address_space(1))) void*)(bSrc[j] + k0),
          (__attribute__((address_space(3))) void*)(BsB + 32768 + (wv * 4 + j) * 1024),
          16, 0, 0);
    }
    __syncthreads();
#pragma unroll
    for (int kk = 0; kk < 2; ++kk) {
      bf16x8 af[4], bfG[4], bfB[4];
#pragma unroll
      for (int i = 0; i < 4; ++i) {
        const int ra = wr + i * 16 + lrow;
        af[i] = *(const bf16x8*)(AsB + ra * 128 + ((((kk << 2) + kg) ^ (ra & 7)) << 4));
        const int rb = wc + i * 16 + lrow;
        const int bo = rb * 128 + ((((kk << 2) + kg) ^ (rb & 7)) << 4);
        bfG[i] = *(const bf16x8*)(BsB + bo);
        bfB[i] = *(const bf16x8*)(BsB + 32768 + bo);
      }
#pragma unroll
      for (int i = 0; i < 4; ++i)
#pragma unroll
        for (int j = 0; j < 4; ++j) {
          accG[i][j] = __builtin_amdgcn_mfma_f32_16x16x32_bf16(af[i], bfG[j], accG[i][j], 0, 0, 0);
          accB[i][j] = __builtin_amdgcn_mfma_f32_16x16x32_bf16(af[i], bfB[j], accB[i][j], 0, 0, 0);
        }
    }
    __syncthreads();
  }

#pragma unroll
  for (int i = 0; i < 4; ++i) {
#pragma unroll
    for (int j = 0; j < 4; ++j) {
      const int col = bn * 256 + wc + j * 16 + lrow;
      const float gvb = bg[col], bvb = bb[col];
      const int row0 = bm * 128 + wr + i * 16 + kg * 4;
#pragma unroll
      for (int rr = 0; rr < 4; ++rr) {
        const int gr = row0 + rr;
        const float gm = accG[i][j][rr] + gvb;
        const float bt = accB[i][j][rr] + bvb;
        const float h = hx[(size_t)gr * N + col];
        hcb[(size_t)gr * N + col] = rnd_bf16((1.f + gm) * h + bt);
      }
    }
  }
}

// ---------------- fp32 -> bf16 convert (8 elems/thread)
__global__ __launch_bounds__(256) void f2b(
    const float4* __restrict__ in, u32x4* __restrict__ out, int n8)
{
  const int i = blockIdx.x * 256 + threadIdx.x;
  if (i < n8) {
    const float4 a = in[2 * i], b = in[2 * i + 1];
    u32x4 o = { pack_bf16(a.x, a.y), pack_bf16(a.z, a.w),
                pack_bf16(b.x, b.y), pack_bf16(b.z, b.w) };
    out[i] = o;
  }
}

// ------- batched small-weight converts: blocks 0-127 W_ga, 128-255 W_gamma,
// 256-383 W_beta, 384-639 W_exp
__global__ __launch_bounds__(256) void f2b4(
    const float4* __restrict__ a, u32x4* __restrict__ oa,
    const float4* __restrict__ b, u32x4* __restrict__ ob,
    const float4* __restrict__ c, u32x4* __restrict__ oc,
    const float4* __restrict__ d, u32x4* __restrict__ od)
{
  const int blk = blockIdx.x;
  const float4* in;
  u32x4* out;
  int base;
  if (blk < 128)      { in = a; out = oa; base = 0; }
  else if (blk < 256) { in = b; out = ob; base = 128; }
  else if (blk < 384) { in = c; out = oc; base = 256; }
  else                { in = d; out = od; base = 384; }
  const int i = (blk - base) * 256 + threadIdx.x;
  const float4 x0 = in[2 * i], x1 = in[2 * i + 1];
  out[i] = u32x4{ pack_bf16(x0.x, x0.y), pack_bf16(x0.z, x0.w),
                  pack_bf16(x1.x, x1.y), pack_bf16(x1.z, x1.w) };
}

// ------- fused: sum 4 split-K partials + bias + LN + GELU + l2norm -> hx,hxb
__global__ __launch_bounds__(256) void gee_fuse_ln1(
    const float* __restrict__ P, const float* __restrict__ b_enc,
    const float* __restrict__ g1, const float* __restrict__ b1,
    float* __restrict__ hx, unsigned int* __restrict__ hxb)
{
  const int row = blockIdx.x, tid = threadIdx.x;
  __shared__ float red[16];
  const size_t MN = (size_t)4096 * 512;
  const size_t o2 = (size_t)row * 256 + tid;
  float2 v = ((const float2*)b_enc)[tid];
#pragma unroll
  for (int qq = 0; qq < 4; ++qq) {
    const float2 p = ((const float2*)P)[qq * (MN / 2) + o2];
    v.x += p.x; v.y += p.y;
  }
  float a = v.x + v.y;
  float b = v.x * v.x + v.y * v.y;
#pragma unroll
  for (int o = 32; o > 0; o >>= 1) { a += __shfl_xor(a, o); b += __shfl_xor(b, o); }
  const int lane = tid & 63, wvi = tid >> 6;
  if (lane == 0) { red[wvi] = a; red[8 + wvi] = b; }
  __syncthreads();
  const float mu  = (red[0] + red[1] + red[2] + red[3]) * (1.f / 512.f);
  const float ex2 = (red[8] + red[9] + red[10] + red[11]) * (1.f / 512.f);
  const float inv = rsqrtf(ex2 - mu * mu + 1e-5f);
  const float2 gg = ((const float2*)g1)[tid];
  const float2 bb = ((const float2*)b1)[tid];
  const float y0 = (v.x - mu) * inv * gg.x + bb.x;
  const float y1 = (v.y - mu) * inv * gg.y + bb.y;
  const float t0 = 0.5f * y0 * (1.f + erff(y0 * 0.70710678118654752f));
  const float t1 = 0.5f * y1 * (1.f + erff(y1 * 0.70710678118654752f));
  float ss = t0 * t0 + t1 * t1;
  __syncthreads();
#pragma unroll
  for (int o = 32; o > 0; o >>= 1) ss += __shfl_xor(ss, o);
  if (lane == 0) red[wvi] = ss;
  __syncthreads();
  const float sc = 1.f / fmaxf(sqrtf(red[0] + red[1] + red[2] + red[3]), 1e-12f);
  const float h0 = t0 * sc, h1 = t1 * sc;
  ((float2*)hx)[o2] = make_float2(h0, h1);
  hxb[o2] = pack_bf16(h0, h1);
}

// ---------------- row l2norm of raw e [20000,512] fp16 -> eb bf16
__global__ __launch_bounds__(256) void gee_l2rows(
    const __half2* __restrict__ ein, unsigned int* __restrict__ eb)
{
  const int row = blockIdx.x, tid = threadIdx.x;
  __shared__ float red[4];
  const __half2 h = ein[(size_t)row * 256 + tid];
  const float vx = __half2float(h.x), vy = __half2float(h.y);
  float ss = vx * vx + vy * vy;
#pragma unroll
  for (int o = 32; o > 0; o >>= 1) ss += __shfl_xor(ss, o);
  if ((tid & 63) == 0) red[tid >> 6] = ss;
  __syncthreads();
  const float sc = 1.f / fmaxf(sqrtf(red[0] + red[1] + red[2] + red[3]), 1e-12f);
  eb[(size_t)row * 256 + tid] = pack_bf16(vx * sc, vy * sc);
}

// -------- top-64 + softmax + fused ctx gather.
// FAST PATH (histogram-free): scan 1 only compacts keys with byte >= SPEC.
// If 64 <= cnt <= CAP, top-64 provably inside the list (>=64 elems above
// SPEC => 64th key >= SPEC<<8 > any non-list key), so 4 ballot nibble
// passes run on the list from pass 0. FALLBACK (cnt<64 or >CAP): exact
// full histogram scan (r11 path) — data-independent correctness.
__global__ __launch_bounds__(256) void gee_topk_ctx(
    const __half* __restrict__ scores, const unsigned int* __restrict__ eb,
    unsigned int* __restrict__ ctxb)
{
  constexpr int G = 20000, GQ = G / 8, CAP = 2048, TCAP = 160;
  constexpr unsigned int SPEC = 0xADu;
  const int row = blockIdx.x, tid = threadIdx.x;
  const int lane = tid & 63, wv = tid >> 6;
  __shared__ int hist[4][256];
  __shared__ int cnt_ge[256];
  __shared__ int wtop[4];
  __shared__ unsigned int comp[CAP];
  __shared__ int whist[4][16];
  __shared__ int sel[64];
  __shared__ float swt[64];
  __shared__ int tie[TCAP];
  __shared__ int s_thr, s_above, s_cand, s_cnt, s_n1, s_n2;

  const u32x4* srow128 = (const u32x4*)((const ushort_t*)scores + (size_t)row * G);
  const ushort_t* srow16 = (const ushort_t*)srow128;

  if (tid == 0) { s_cnt = 0; s_n1 = 0; s_n2 = 0; s_thr = 0; s_above = 0; }
  __syncthreads();

  // ---- scan 1 (vectorized): compact-only, no histogram
  for (int j0 = 0; j0 < GQ; j0 += 256) {
    const int j = j0 + tid;
    if (j < GQ) {
      const u32x4 pv = srow128[j];
#pragma unroll
      for (int c = 0; c < 4; ++c) {
        const unsigned int p = pv[c];
        const unsigned int f = (((p >> 15) & 0x10001u) * 0x7FFFu) + 0x80008000u;
        const unsigned int k2 = p ^ f;
        const unsigned int lo = k2 & 0xFFFFu, hi = k2 >> 16;
        if ((lo >> 8) >= SPEC) {
          const int pp = atomicAdd(&s_cnt, 1);
          if (pp < CAP) comp[pp] = (lo << 16) | (unsigned)(8 * j + 2 * c);
        }
        if ((hi >> 8) >= SPEC) {
          const int pp = atomicAdd(&s_cnt, 1);
          if (pp < CAP) comp[pp] = (hi << 16) | (unsigned)(8 * j + 2 * c + 1);
        }
      }
    }
  }
  __syncthreads();

  const int cnt1 = s_cnt;
  const bool fast = (cnt1 >= 64 && cnt1 <= CAP);
  int passBeg;
  bool useComp;
  int Nloop;

  if (fast) {
    passBeg = 0;
    useComp = true;
    Nloop = cnt1;
  } else {
    // ---- fallback: exact byte-histogram over the full score row
#pragma unroll
    for (int b = 0; b < 4; ++b) hist[b][tid] = 0;
    __syncthreads();
    for (int j0 = 0; j0 < GQ; j0 += 256) {
      const int j = j0 + tid;
      if (j < GQ) {
        const u32x4 pv = srow128[j];
#pragma unroll
        for (int c = 0; c < 4; ++c) {
          const unsigned int p = pv[c];
          const unsigned int f = (((p >> 15) & 0x10001u) * 0x7FFFu) + 0x80008000u;
          const unsigned int k2 = p ^ f;
          atomicAdd(&hist[wv][(k2 >> 8) & 0xFFu], 1);
          atomicAdd(&hist[wv][k2 >> 24], 1);
        }
      }
    }
    __syncthreads();
    cnt_ge[tid] = hist[0][tid] + hist[1][tid] + hist[2][tid] + hist[3][tid];
    __syncthreads();
    for (int off = 1; off < 256; off <<= 1) {
      const int add = (tid + off < 256) ? cnt_ge[tid + off] : 0;
      __syncthreads();
      cnt_ge[tid] += add;
      __syncthreads();
    }
    {
      const unsigned long long m = __ballot(cnt_ge[tid] >= 64);
      if (lane == 0) wtop[wv] = m ? (wv * 64 + 63 - __clzll(m)) : -1;
    }
    __syncthreads();
    if (tid == 0) {
      const int thrB = max(max(wtop[0], wtop[1]), max(wtop[2], wtop[3]));
      s_cand  = cnt_ge[thrB];
      s_above = (thrB == 255) ? 0 : cnt_ge[thrB + 1];
      s_thr   = thrB << 8;
      s_cnt   = 0;
    }
    __syncthreads();
    const unsigned int thrB = ((unsigned int)s_thr) >> 8;
    useComp = (s_cand <= CAP);
    if (useComp) {
      for (int j0 = 0; j0 < GQ; j0 += 256) {
        const int j = j0 + tid;
        if (j < GQ) {
          const u32x4 pv = srow128[j];
#pragma unroll
          for (int c = 0; c < 4; ++c) {
            const unsigned int p = pv[c];
            const unsigned int f = (((p >> 15) & 0x10001u) * 0x7FFFu) + 0x80008000u;
            const unsigned int k2 = p ^ f;
            const unsigned int lo = k2 & 0xFFFFu, hi = k2 >> 16;
            if ((lo >> 8) >= thrB) {
              const int pp = atomicAdd(&s_cnt, 1);
              comp[pp] = (lo << 16) | (unsigned)(8 * j + 2 * c);
            }
            if ((hi >> 8) >= thrB) {
              const int pp = atomicAdd(&s_cnt, 1);
              comp[pp] = (hi << 16) | (unsigned)(8 * j + 2 * c + 1);
            }
          }
        }
      }
    }
    __syncthreads();
    passBeg = 2;
    Nloop = useComp ? s_cnt : G;
  }

  // ---- ballot nibble passes (fast: 0..3 on list; fallback: 2..3)
  for (int pass = passBeg; pass < 4; ++pass) {
    const int shift = 12 - 4 * pass;
    const unsigned int thr = (unsigned int)s_thr;
    const unsigned int pfx = thr >> (shift + 4);
    int c[16];
#pragma unroll
    for (int b = 0; b < 16; ++b) c[b] = 0;
    for (int j0 = 0; j0 < Nloop; j0 += 256) {
      const int j = j0 + tid;
      const bool ok = j < Nloop;
      unsigned int key;
      if (useComp) {
        key = ok ? (comp[j] >> 16) : 0u;
      } else {
        const unsigned int raw = ok ? (unsigned int)srow16[j] : 0u;
        key = (raw & 0x8000u) ? (0xFFFFu & ~raw) : (raw | 0x8000u);
      }
      const unsigned int nb = (ok && (key >> (shift + 4)) == pfx) ? ((key >> shift) & 15u) : 0xFFu;
#pragma unroll
      for (int b = 0; b < 16; ++b) c[b] += __popcll(__ballot(nb == (unsigned)b));
    }
    if (lane == 0) {
#pragma unroll
      for (int b = 0; b < 16; ++b) whist[wv][b] = c[b];
    }
    __syncthreads();
    if (tid == 0) {
      int run = s_above;
      for (int vv = 15; vv >= 0; --vv) {
        const int c4 = whist[0][vv] + whist[1][vv] + whist[2][vv] + whist[3][vv];
        if (run + c4 >= 64) { s_thr |= vv << shift; break; }
        run += c4;
      }
      s_above = run;
    }
    __syncthreads();
  }

  // ---- selection (non-list keys < SPEC<<8 <= kthr strictly; safe)
  const unsigned int kthr = (unsigned int)s_thr;
  for (int j0 = 0; j0 < Nloop; j0 += 256) {
    const int j = j0 + tid;
    if (j < Nloop) {
      unsigned int key, idx;
      if (useComp) {
        const unsigned int u = comp[j];
        key = u >> 16; idx = u & 0xFFFFu;
      } else {
        const unsigned int raw = (unsigned int)srow16[j];
        key = (raw & 0x8000u) ? (0xFFFFu & ~raw) : (raw | 0x8000u);
        idx = (unsigned)j;
      }
      if (key > kthr) {
        const int pp = atomicAdd(&s_n1, 1);
        sel[pp] = (int)idx;
      } else if (key == kthr) {
        const int pp = atomicAdd(&s_n2, 1);
        if (pp < TCAP) tie[pp] = (int)idx;
      }
    }
  }
  __syncthreads();
  if (tid == 0) {
    const int n1 = s_n1;
    const int n2 = min(s_n2, TCAP);
    const int need = 64 - n1;
    for (int rr = 0; rr < need; ++rr) {       // smallest indices (top_k tie-break)
      int best = 1 << 30, bj = 0;
      for (int j = 0; j < n2; ++j)
        if (tie[j] < best) { best = tie[j]; bj = j; }
      sel[n1 + rr] = best;
      tie[bj] = 1 << 30;
    }
  }
  __syncthreads();
  if (tid < 64) {
    const int idx = sel[tid];
    const float sv = __half2float(scores[(size_t)row * G + idx]) * 10.0f;  // 1/T
    float m = sv;
#pragma unroll
    for (int o = 32; o > 0; o >>= 1) m = fmaxf(m, __shfl_xor(m, o));
    const float w = __expf(sv - m);
    float d = w;
#pragma unroll
    for (int o = 32; o > 0; o >>= 1) d += __shfl_xor(d, o);
    swt[tid] = w / d;
  }
  __syncthreads();
  float a0 = 0.f, a1 = 0.f;
#pragma unroll 4
  for (int k = 0; k < 64; ++k) {
    const unsigned int pk = eb[(size_t)sel[k] * 256 + tid];
    const float wk = swt[k];
    a0 += wk * __uint_as_float(pk << 16);
    a1 += wk * __uint_as_float(pk & 0xFFFF0000u);
  }
  ctxb[(size_t)row * 256 + tid] = pack_bf16(a0, a1);
}

// ---------------- LN2 + exact GELU -> out [4096,1024]
__global__ __launch_bounds__(256) void gee_ln2(
    const float* __restrict__ h2, const float* __restrict__ g2,
    const float* __restrict__ b2, float* __restrict__ out)
{
  const int row = blockIdx.x, tid = threadIdx.x;
  __shared__ float red[16];
  float v[4];
  float a = 0.f, b = 0.f;
#pragma unroll
  for (int e = 0; e < 4; ++e) {
    v[e] = h2[(size_t)row * 1024 + tid + e * 256];
    a += v[e]; b += v[e] * v[e];
  }
#pragma unroll
  for (int o = 32; o > 0; o >>= 1) { a += __shfl_xor(a, o); b += __shfl_xor(b, o); }
  const int lane = tid & 63, wvi = tid >> 6;
  if (lane == 0) { red[wvi] = a; red[8 + wvi] = b; }
  __syncthreads();
  const float mu  = (red[0] + red[1] + red[2] + red[3]) * (1.f / 1024.f);
  const float ex2 = (red[8] + red[9] + red[10] + red[11]) * (1.f / 1024.f);
  const float inv = rsqrtf(ex2 - mu * mu + 1e-5f);
#pragma unroll
  for (int e = 0; e < 4; ++e) {
    const int c = tid + e * 256;
    const float y = (v[e] - mu) * inv * g2[c] + b2[c];
    out[(size_t)row * 1024 + c] = 0.5f * y * (1.f + erff(y * 0.70710678118654752f));
  }
}

extern "C" void kernel_launch(void* const* d_in, const int* in_sizes, int n_in,
                              void* d_out, int out_size, void* d_ws, size_t ws_size,
                              hipStream_t stream)
{
  const float* x       = (const float*)d_in[0];
  const float* g       = (const float*)d_in[1];
  const float* W_enc   = (const float*)d_in[2];
  const float* b_enc   = (const float*)d_in[3];
  const float* ln1_g   = (const float*)d_in[4];
  const float* ln1_b   = (const float*)d_in[5];
  const float* W_ga    = (const float*)d_in[6];
  const float* W_gamma = (const float*)d_in[7];
  const float* b_gamma = (const float*)d_in[8];
  const float* W_beta  = (const float*)d_in[9];
  const float* b_beta  = (const float*)d_in[10];
  const float* W_exp   = (const float*)d_in[11];
  const float* b_exp   = (const float*)d_in[12];
  const float* ln2_g   = (const float*)d_in[13];
  const float* ln2_b   = (const float*)d_in[14];
  float* out = (float*)d_out;

  char* ws = (char*)d_ws;
  constexpr size_t OFF_SCORES = 0;            // 163,840,000 (t5-t6)
  constexpr size_t OFF_H2     = 0;            // 16,777,216 (t10+, scores dead)
  constexpr size_t OFF_PART   = 163840000;    // 33,554,432
  constexpr size_t OFF_WENCB  = 197394432;    // 20,480,000 (t0-t1) -> e (t3-t4)
  constexpr size_t OFF_E      = 197394432;    // alias
  constexpr size_t OFF_EB     = 217874432;    // 20,480,000
  constexpr size_t OFF_HX     = 238354432;    // 8,388,608
  constexpr size_t OFF_HXB    = 246743040;    // 4,194,304
  constexpr size_t OFF_CTXB   = 250937344;    // 4,194,304
  constexpr size_t OFF_HCB    = 255131648;    // 4,194,304
  constexpr size_t OFF_WGAB   = 259325952;    // 524,288
  constexpr size_t OFF_WGMB   = 259850240;    // 524,288
  constexpr size_t OFF_WBTB   = 260374528;    // 524,288
  constexpr size_t OFF_WEXB   = 260898816;    // 1,048,576 -> total 261,947,392

  __half*       scores = (__half*)(ws + OFF_SCORES);
  float*        h2     = (float*)(ws + OFF_H2);
  float*        part   = (float*)(ws + OFF_PART);
  ushort_t*     wencb  = (ushort_t*)(ws + OFF_WENCB);
  __half*       e      = (__half*)(ws + OFF_E);
  unsigned int* eb     = (unsigned int*)(ws + OFF_EB);
  float*        hx     = (float*)(ws + OFF_HX);
  unsigned int* hxb    = (unsigned int*)(ws + OFF_HXB);
  unsigned int* ctxb   = (unsigned int*)(ws + OFF_CTXB);
  ushort_t*     hcb    = (ushort_t*)(ws + OFF_HCB);
  ushort_t*     wgab   = (ushort_t*)(ws + OFF_WGAB);
  ushort_t*     wgmb   = (ushort_t*)(ws + OFF_WGMB);
  ushort_t*     wbtb   = (ushort_t*)(ws + OFF_WBTB);
  ushort_t*     wexb   = (ushort_t*)(ws + OFF_WEXB);

  // 0) weight converts fp32 -> bf16 (W_enc big; 4 small weights batched)
  f2b<<<5000, 256, 0, stream>>>((const float4*)W_enc, (u32x4*)wencb, 1280000);
  f2b4<<<640, 256, 0, stream>>>(
      (const float4*)W_ga,    (u32x4*)wgab,
      (const float4*)W_gamma, (u32x4*)wgmb,
      (const float4*)W_beta,  (u32x4*)wbtb,
      (const float4*)W_exp,   (u32x4*)wexb);

  // 1) split-K=4 partials of x(fp32) @ wencb^T -> part[4][4096][512]
  bgemmA32<4, true, float><<<256, 512, 0, stream>>>(
      x, wencb, part, 4096, 512, 20000, 2, 32);
  // 2) h_x = l2norm(gelu(LN1(sum partials + b_enc)))
  gee_fuse_ln1<<<4096, 256, 0, stream>>>(part, b_enc, ln1_g, ln1_b, hx, hxb);
  // 3) e_raw = g @ W_ga^T  [20000][512] fp16 (single-buf, 2/CU; r13 lesson)
  bgemm<float, 1, false, __half><<<314, 512, 0, stream>>>(
      g, wgab, nullptr, e, 20000, 512, 512, 2, 157);
  // 4) eb = l2norm rows (bf16)
  gee_l2rows<<<20000, 256, 0, stream>>>((const __half2*)e, eb);
  // 5) scores = hxb @ eb^T  (fp16 out)
  bgemm256<1, __half><<<1264, 512, 0, stream>>>(
      (const ushort_t*)hxb, (const ushort_t*)eb, scores, 4096, 20000, 512, 79, 16);
  // 6+7) top-64 + softmax + fused ctx gather -> ctxb (histogram-free fast path)
  gee_topk_ctx<<<4096, 256, 0, stream>>>(scores, eb, ctxb);
  // 8+9) FiLM: gamma,beta GEMMs + (1+g)*hx+b fused -> hcb bf16
  bgemm_film<<<64, 512, 0, stream>>>(
      (const ushort_t*)ctxb, wgmb, wbtb, b_gamma, b_beta, hx, hcb);
  // 10) h2 = h_cell @ W_exp^T + b_exp  (bf16-A)
  bgemm<ushort_t, 1, true, float><<<128, 512, 0, stream>>>(
      hcb, wexb, b_exp, h2, 4096, 1024, 512, 4, 32);
  // 11) out = gelu(LN2(h2))
  gee_ln2<<<4096, 256, 0, stream>>>(h2, ln2_g, ln2_b, out);
}

// Round 16
// 476.792 us; speedup vs baseline: 1.0123x; 1.0123x over previous
//
#include <hip/hip_runtime.h>
#include <hip/hip_fp16.h>
#include <math.h>
#include <type_traits>

#define DEVI __device__ __forceinline__

typedef __attribute__((ext_vector_type(8))) short bf16x8;
typedef __attribute__((ext_vector_type(4))) float f32x4;
typedef __attribute__((ext_vector_type(4))) unsigned int u32x4;
typedef unsigned short ushort_t;

DEVI unsigned int pack_bf16(float a, float b) {
  unsigned int ua = __float_as_uint(a), ub = __float_as_uint(b);
  ua = (ua + 0x7FFFu + ((ua >> 16) & 1u)) >> 16;   // RNE
  ub = (ub + 0x7FFFu + ((ub >> 16) & 1u)) >> 16;
  return ua | (ub << 16);
}

DEVI ushort_t rnd_bf16(float a) {
  unsigned int ua = __float_as_uint(a);
  return (ushort_t)((ua + 0x7FFFu + ((ua >> 16) & 1u)) >> 16);
}

DEVI bf16x8 cvt_bf16x8(f32x4 lo, f32x4 hi) {
  unsigned int r0, r1, r2, r3;
  asm("v_cvt_pk_bf16_f32 %0, %1, %2" : "=v"(r0) : "v"(lo[0]), "v"(lo[1]));
  asm("v_cvt_pk_bf16_f32 %0, %1, %2" : "=v"(r1) : "v"(lo[2]), "v"(lo[3]));
  asm("v_cvt_pk_bf16_f32 %0, %1, %2" : "=v"(r2) : "v"(hi[0]), "v"(hi[1]));
  asm("v_cvt_pk_bf16_f32 %0, %1, %2" : "=v"(r3) : "v"(hi[2]), "v"(hi[3]));
  union { u32x4 u; bf16x8 v; } x;
  x.u = u32x4{r0, r1, r2, r3};
  return x.v;
}

// =======================================================================
// bgemmA32: C[M,N] = A_fp32[M,K] * B_bf16[N,K]^T, 4-phase counted-vmcnt
// pipeline, BM=128, BN=256, BK=64, 8 waves. LDS 128KB dbuf (1 block/CU —
// only use when grid <= 256 and K large; r13 post-mortem). A converted
// bf16 at frag read (v_cvt_pk RNE). Peeled reg-staged 32-tail on last z.
// =======================================================================
template<int SPLITZ, bool TAIL, typename OutT>
__global__ __launch_bounds__(512, 1) void bgemmA32(
    const float* __restrict__ A, const ushort_t* __restrict__ B,
    OutT* __restrict__ C, int M, int N, int K, int nbn, int nbm)
{
  __shared__ __align__(16) char L[131072];  // A:[0,64K) B:[64K,128K)
  const int tid = threadIdx.x, lane = tid & 63, wv = tid >> 6;

  const int nwg = gridDim.x;
  const int hw = blockIdx.x;
  const int q = nwg >> 3, r = nwg & 7;
  const int xcd = hw & 7, pos = hw >> 3;
  const int lid = (xcd < r ? xcd * (q + 1) : r * (q + 1) + (xcd - r) * q) + pos;
  const int bn = lid % nbn;
  const int t2 = lid / nbn;
  const int bm = t2 % nbm;
  const int z  = t2 / nbm;

  const int ksteps = K >> 6;
  const int szk = (ksteps + SPLITZ - 1) / SPLITZ;
  const int kbBeg = z * szk;
  const int kbEnd = min(ksteps, kbBeg + szk);

  const int wm = wv >> 2, wn = wv & 3;
  const int lrow = lane & 15, kg = lane >> 4;

  f32x4 acc[4][4];
#pragma unroll
  for (int i = 0; i < 4; ++i)
#pragma unroll
    for (int j = 0; j < 4; ++j) acc[i][j] = f32x4{0.f, 0.f, 0.f, 0.f};

  const int alr = lane >> 3, ag32 = (lane & 7) >> 1;
  const float* aS[2];
#pragma unroll
  for (int j = 0; j < 2; ++j) {
    const int lr = (wv * 2 + j) * 8 + alr;
    const int swz = (lr ^ (lr >> 2)) & 3;
    const int colf = ((ag32 ^ swz) << 3) + (lane & 1) * 4;
    aS[j] = A + (size_t)min(bm * 128 + lr, M - 1) * (size_t)K + colf;
  }
  const int blr = lane >> 2, bgq = lane & 3;
  const ushort_t* bS[2];
#pragma unroll
  for (int j = 0; j < 2; ++j) {
    const int lr = (wv * 2 + j) * 16 + blr;
    const int swz = (lr ^ (lr >> 2)) & 3;
    bS[j] = B + (size_t)min(bn * 256 + lr, N - 1) * (size_t)K + ((bgq ^ swz) << 3);
  }

  int offA[4], offB[4];
#pragma unroll
  for (int i = 0; i < 4; ++i) {
    const int ra = wm * 64 + i * 16 + lrow;
    offA[i] = ra * 128 + ((kg ^ ((ra ^ (ra >> 2)) & 3)) << 5);
  }
#pragma unroll
  for (int j = 0; j < 4; ++j) {
    const int rb = wn * 64 + j * 16 + lrow;
    offB[j] = rb * 64 + ((kg ^ ((rb ^ (rb >> 2)) & 3)) << 4);
  }

#define GA_STGA(h, k0v) do {                                                  \
    _Pragma("unroll")                                                         \
    for (int j_ = 0; j_ < 2; ++j_)                                            \
      __builtin_amdgcn_global_load_lds(                                       \
          (const __attribute__((address_space(1))) void*)(aS[j_] + (k0v) + (h) * 32), \
          (__attribute__((address_space(3))) void*)                           \
              (L + (s ^ 1) * 32768 + (h) * 16384 + (wv * 2 + j_) * 1024),     \
          16, 0, 0);                                                          \
  } while (0)
#define GA_STGB(h, k0v) do {                                                  \
    _Pragma("unroll")                                                         \
    for (int j_ = 0; j_ < 2; ++j_)                                            \
      __builtin_amdgcn_global_load_lds(                                       \
          (const __attribute__((address_space(1))) void*)(bS[j_] + (k0v) + (h) * 32), \
          (__attribute__((address_space(3))) void*)                           \
              (L + 65536 + (s ^ 1) * 32768 + (h) * 16384 + (wv * 2 + j_) * 1024), \
          16, 0, 0);                                                          \
  } while (0)
#define GA_RDB(h) do {                                                        \
    _Pragma("unroll")                                                         \
    for (int j_ = 0; j_ < 4; ++j_)                                            \
      bfv[j_] = *(const bf16x8*)(L + 65536 + s * 32768 + (h) * 16384 + offB[j_]); \
  } while (0)
#define GA_RDA(h, rg) do {                                                    \
    _Pragma("unroll")                                                         \
    for (int i_ = 0; i_ < 2; ++i_) {                                          \
      const char* pa_ = L + s * 32768 + (h) * 16384 + offA[(rg) * 2 + i_];    \
      af[i_] = cvt_bf16x8(*(const f32x4*)pa_, *(const f32x4*)(pa_ + 16));     \
    }                                                                         \
  } while (0)
#define GA_MM(rg) do {                                                        \
    _Pragma("unroll")                                                         \
    for (int i_ = 0; i_ < 2; ++i_)                                            \
      _Pragma("unroll")                                                       \
      for (int j_ = 0; j_ < 4; ++j_)                                          \
        acc[(rg) * 2 + i_][j_] = __builtin_amdgcn_mfma_f32_16x16x32_bf16(     \
            af[i_], bfv[j_], acc[(rg) * 2 + i_][j_], 0, 0, 0);                \
  } while (0)
#define GA_BAR asm volatile("s_barrier" ::: "memory")

  {
    int s = 1;
    const int k0 = kbBeg << 6;
    GA_STGA(0, k0); GA_STGB(0, k0); GA_STGA(1, k0); GA_STGB(1, k0);
  }
  asm volatile("s_waitcnt vmcnt(4)" ::: "memory");
  GA_BAR;

  int s = 0;
  for (int t = kbBeg; t < kbEnd; ++t) {
    const bool more = (t + 1 < kbEnd);
    const int k0n = (t + 1) << 6;
    bf16x8 af[2], bfv[4];
    GA_RDB(0); GA_RDA(0, 0);
    if (more) GA_STGA(0, k0n);
    GA_BAR;
    __builtin_amdgcn_s_setprio(1); GA_MM(0); __builtin_amdgcn_s_setprio(0);
    GA_BAR;
    GA_RDA(0, 1);
    if (more) GA_STGB(0, k0n);
    GA_BAR;
    __builtin_amdgcn_s_setprio(1); GA_MM(1); __builtin_amdgcn_s_setprio(0);
    if (more) asm volatile("s_waitcnt vmcnt(4)" ::: "memory");
    else      asm volatile("s_waitcnt vmcnt(0)" ::: "memory");
    GA_BAR;
    GA_RDB(1); GA_RDA(1, 0);
    if (more) GA_STGA(1, k0n);
    GA_BAR;
    __builtin_amdgcn_s_setprio(1); GA_MM(0); __builtin_amdgcn_s_setprio(0);
    GA_BAR;
    GA_RDA(1, 1);
    if (more) GA_STGB(1, k0n);
    GA_BAR;
    __builtin_amdgcn_s_setprio(1); GA_MM(1); __builtin_amdgcn_s_setprio(0);
    if (more) asm volatile("s_waitcnt vmcnt(4)" ::: "memory");
    GA_BAR;
    s ^= 1;
  }

  if (TAIL && z == SPLITZ - 1 && (K & 63)) {
    const int k0t = ksteps << 6;
    bf16x8 af[2], bfv[4];
#pragma unroll
    for (int j = 0; j < 2; ++j) {
      const float4 av = *(const float4*)(aS[j] + k0t);
      *(float4*)(L + s * 32768 + (wv * 2 + j) * 1024 + lane * 16) = av;
      const u32x4 bv = *(const u32x4*)(bS[j] + k0t);
      *(u32x4*)(L + 65536 + s * 32768 + (wv * 2 + j) * 1024 + lane * 16) = bv;
    }
    __syncthreads();
    GA_RDB(0);
    GA_RDA(0, 0); GA_MM(0);
    GA_RDA(0, 1); GA_MM(1);
  }
#undef GA_STGA
#undef GA_STGB
#undef GA_RDB
#undef GA_RDA
#undef GA_MM
#undef GA_BAR

  const size_t zoff = (SPLITZ > 1) ? (size_t)z * (size_t)M * (size_t)N : 0;
#pragma unroll
  for (int i = 0; i < 4; ++i) {
#pragma unroll
    for (int j = 0; j < 4; ++j) {
      const int col = bn * 256 + wn * 64 + j * 16 + lrow;
      if (col >= N) continue;
      const int row0 = bm * 128 + wm * 64 + i * 16 + kg * 4;
#pragma unroll
      for (int rr = 0; rr < 4; ++rr) {
        const int gr = row0 + rr;
        if (gr < M) {
          const float v = acc[i][j][rr];
          if constexpr (std::is_same<OutT, __half>::value)
            C[zoff + (size_t)gr * (size_t)N + col] = __float2half(v);
          else
            C[zoff + (size_t)gr * (size_t)N + col] = v;
        }
      }
    }
  }
}

// =======================================================================
// bgemm256: all-bf16 256x256 4-phase pipeline. K%64==0. No epilogue
// side-effects (r12 lesson: divergent atomics in wide epilogue = 11x).
// =======================================================================
template<int SPLITZ, typename OutT>
__global__ __launch_bounds__(512, 1) void bgemm256(
    const ushort_t* __restrict__ A, const ushort_t* __restrict__ B,
    OutT* __restrict__ C, int M, int N, int K, int nbn, int nbm)
{
  __shared__ __align__(16) char L[131072];
  const int tid = threadIdx.x, lane = tid & 63, wv = tid >> 6;

  const int nwg = gridDim.x;
  const int hw = blockIdx.x;
  const int q = nwg >> 3, r = nwg & 7;
  const int xcd = hw & 7, pos = hw >> 3;
  const int lid = (xcd < r ? xcd * (q + 1) : r * (q + 1) + (xcd - r) * q) + pos;
  const int bn = lid % nbn;
  const int t2 = lid / nbn;
  const int bm = t2 % nbm;
  const int z  = t2 / nbm;

  const int ksteps = K >> 6;
  int kbBeg = 0, kbEnd = ksteps;
  if (SPLITZ > 1) {
    const int sz = (ksteps + SPLITZ - 1) / SPLITZ;
    kbBeg = z * sz;
    kbEnd = min(ksteps, kbBeg + sz);
  }

  const int wm = wv >> 2, wn = wv & 3;
  const int lrow = lane & 15, kg = lane >> 4;

  f32x4 acc[8][4];
#pragma unroll
  for (int i = 0; i < 8; ++i)
#pragma unroll
    for (int j = 0; j < 4; ++j) acc[i][j] = f32x4{0.f, 0.f, 0.f, 0.f};

  const int sr = lane >> 2, sq = lane & 3;
  const ushort_t* aS[2];
  const ushort_t* bS[2];
#pragma unroll
  for (int j = 0; j < 2; ++j) {
    const int lr = (wv * 2 + j) * 16 + sr;
    const int swz = (lr ^ (lr >> 2)) & 3;
    aS[j] = A + (size_t)min(bm * 256 + lr, M - 1) * (size_t)K + ((sq ^ swz) << 3);
    bS[j] = B + (size_t)min(bn * 256 + lr, N - 1) * (size_t)K + ((sq ^ swz) << 3);
  }

  int offA[8], offB[4];
#pragma unroll
  for (int i = 0; i < 8; ++i) {
    const int ra = wm * 128 + i * 16 + lrow;
    offA[i] = ra * 64 + (((kg ^ ((ra ^ (ra >> 2)) & 3))) << 4);
  }
#pragma unroll
  for (int j = 0; j < 4; ++j) {
    const int rb = wn * 64 + j * 16 + lrow;
    offB[j] = rb * 64 + (((kg ^ ((rb ^ (rb >> 2)) & 3))) << 4);
  }

#define G256_STG(isB, h, k0v) do {                                            \
    _Pragma("unroll")                                                         \
    for (int j_ = 0; j_ < 2; ++j_)                                            \
      __builtin_amdgcn_global_load_lds(                                       \
          (const __attribute__((address_space(1))) void*)                     \
              (((isB) ? bS : aS)[j_] + (k0v) + (h) * 32),                     \
          (__attribute__((address_space(3))) void*)                           \
              (L + (isB) * 65536 + (s ^ 1) * 32768 + (h) * 16384 +            \
               (wv * 2 + j_) * 1024), 16, 0, 0);                              \
  } while (0)
#define G256_RDA(h, rg) do {                                                  \
    _Pragma("unroll")                                                         \
    for (int i_ = 0; i_ < 4; ++i_)                                            \
      af[i_] = *(const bf16x8*)(L + s * 32768 + (h) * 16384 +                 \
                                offA[(rg) * 4 + i_]);                         \
  } while (0)
#define G256_RDB(h) do {                                                      \
    _Pragma("unroll")                                                         \
    for (int j_ = 0; j_ < 4; ++j_)                                            \
      bfv[j_] = *(const bf16x8*)(L + 65536 + s * 32768 + (h) * 16384 +        \
                                 offB[j_]);                                   \
  } while (0)
#define G256_MM(rg) do {                                                      \
    _Pragma("unroll")                                                         \
    for (int i_ = 0; i_ < 4; ++i_)                                            \
      _Pragma("unroll")                                                       \
      for (int j_ = 0; j_ < 4; ++j_)                                          \
        acc[(rg) * 4 + i_][j_] = __builtin_amdgcn_mfma_f32_16x16x32_bf16(     \
            af[i_], bfv[j_], acc[(rg) * 4 + i_][j_], 0, 0, 0);                \
  } while (0)
#define G256_BAR asm volatile("s_barrier" ::: "memory")

  {
    int s = 1;
    const int k0 = kbBeg << 6;
    G256_STG(0, 0, k0);
    G256_STG(1, 0, k0);
    G256_STG(0, 1, k0);
    G256_STG(1, 1, k0);
  }
  asm volatile("s_waitcnt vmcnt(4)" ::: "memory");
  G256_BAR;

  int s = 0;
  for (int t = kbBeg; t < kbEnd; ++t) {
    const bool more = (t + 1 < kbEnd);
    const int k0n = (t + 1) << 6;
    bf16x8 af[4], bfv[4];
    G256_RDB(0);
    G256_RDA(0, 0);
    if (more) G256_STG(0, 0, k0n);
    G256_BAR;
    __builtin_amdgcn_s_setprio(1); G256_MM(0); __builtin_amdgcn_s_setprio(0);
    G256_BAR;
    G256_RDA(0, 1);
    if (more) G256_STG(1, 0, k0n);
    G256_BAR;
    __builtin_amdgcn_s_setprio(1); G256_MM(1); __builtin_amdgcn_s_setprio(0);
    if (more) asm volatile("s_waitcnt vmcnt(4)" ::: "memory");
    else      asm volatile("s_waitcnt vmcnt(0)" ::: "memory");
    G256_BAR;
    G256_RDB(1);
    G256_RDA(1, 0);
    if (more) G256_STG(0, 1, k0n);
    G256_BAR;
    __builtin_amdgcn_s_setprio(1); G256_MM(0); __builtin_amdgcn_s_setprio(0);
    G256_BAR;
    G256_RDA(1, 1);
    if (more) G256_STG(1, 1, k0n);
    G256_BAR;
    __builtin_amdgcn_s_setprio(1); G256_MM(1); __builtin_amdgcn_s_setprio(0);
    if (more) asm volatile("s_waitcnt vmcnt(4)" ::: "memory");
    G256_BAR;
    s ^= 1;
  }
#undef G256_STG
#undef G256_RDA
#undef G256_RDB
#undef G256_MM
#undef G256_BAR

  const size_t zoff = (SPLITZ > 1) ? (size_t)z * (size_t)M * (size_t)N : 0;
#pragma unroll
  for (int i = 0; i < 8; ++i) {
#pragma unroll
    for (int j = 0; j < 4; ++j) {
      const int col = bn * 256 + wn * 64 + j * 16 + lrow;
      if (col >= N) continue;
      const int row0 = bm * 256 + wm * 128 + i * 16 + kg * 4;
#pragma unroll
      for (int rr = 0; rr < 4; ++rr) {
        const int gr = row0 + rr;
        if (gr < M) {
          const float v = acc[i][j][rr];
          if constexpr (std::is_same<OutT, __half>::value)
            C[zoff + (size_t)gr * (size_t)N + col] = __float2half(v);
          else
            C[zoff + (size_t)gr * (size_t)N + col] = v;
        }
      }
    }
  }
}

// =======================================================================
// old bgemm (e-GEMM / GEMM4): 128x256, BK=64, 8 waves, single-buf.
// fp32-A: 2 blocks/CU; bf16-A: 3 blocks/CU. Best for short-K / big grids.
// =======================================================================
template<typename AT, int SPLITZ, bool BIAS, typename OutT>
__global__ __launch_bounds__(512, sizeof(AT) == 2 ? 3 : 2) void bgemm(
    const AT* __restrict__ A, const ushort_t* __restrict__ B0,
    const float* __restrict__ bias0, OutT* __restrict__ C,
    int M, int N, int K, int nbn, int nbm)
{
  constexpr bool AB16 = (sizeof(AT) == 2);
  __shared__ __align__(16) char AsB[AB16 ? 16384 : 32768];
  __shared__ __align__(16) char BsB[32768];
  const int tid = threadIdx.x, lane = tid & 63, wv = tid >> 6;

  const int nwg = gridDim.x;
  const int hw = blockIdx.x;
  const int q = nwg >> 3, r = nwg & 7;
  const int xcd = hw & 7, pos = hw >> 3;
  const int lid = (xcd < r ? xcd * (q + 1) : r * (q + 1) + (xcd - r) * q) + pos;
  const int bn = lid % nbn;
  const int t2 = lid / nbn;
  const int bm = t2 % nbm;
  const int z  = t2 / nbm;

  const ushort_t* B  = B0;
  const float* bias  = bias0;

  const int ksteps = (K + 63) >> 6;
  int kbBeg = 0, kbEnd = ksteps;
  if (SPLITZ > 1) {
    const int sz = (ksteps + SPLITZ - 1) / SPLITZ;
    kbBeg = z * sz;
    kbEnd = min(ksteps, kbBeg + sz);
  }

  const int wr = (wv >> 2) * 64;
  const int wc = (wv & 3) * 64;
  const int lrow = lane & 15, kg = lane >> 4;

  f32x4 acc[4][4];
#pragma unroll
  for (int i = 0; i < 4; ++i)
#pragma unroll
    for (int j = 0; j < 4; ++j) acc[i][j] = f32x4{0.f, 0.f, 0.f, 0.f};

  const AT* aSrc[4];
  if constexpr (AB16) {
    const int r0 = lane >> 3;
    const int ce = ((lane & 7) ^ r0) << 3;
#pragma unroll
    for (int j = 0; j < 2; ++j) {
      const int row = wv * 16 + j * 8 + r0;
      aSrc[j] = A + (size_t)min(bm * 128 + row, M - 1) * (size_t)K + ce;
    }
  } else {
    const int r0 = lane >> 4;
#pragma unroll
    for (int j = 0; j < 4; ++j) {
      const int row = wv * 16 + j * 4 + r0;
      const int ca = ((lane & 15) << 2) ^ ((row & 7) << 3);
      aSrc[j] = A + (size_t)min(bm * 128 + row, M - 1) * (size_t)K + ca;
    }
  }
  const int rB0 = lane >> 3;
  const int colB = ((lane & 7) ^ rB0) << 3;
  const ushort_t* bSrc[4];
#pragma unroll
  for (int j = 0; j < 4; ++j) {
    const int row = wv * 32 + j * 8 + rB0;
    bSrc[j] = B + (size_t)min(bn * 256 + row, N - 1) * (size_t)K + colB;
  }

  for (int kb = kbBeg; kb < kbEnd; ++kb) {
    const int k0 = kb << 6;
    if constexpr (AB16) {
#pragma unroll
      for (int j = 0; j < 2; ++j)
        __builtin_amdgcn_global_load_lds(
            (const __attribute__((address_space(1))) void*)(aSrc[j] + k0),
            (__attribute__((address_space(3))) void*)(AsB + (wv * 2 + j) * 1024),
            16, 0, 0);
    } else {
#pragma unroll
      for (int j = 0; j < 4; ++j)
        __builtin_amdgcn_global_load_lds(
            (const __attribute__((address_space(1))) void*)(aSrc[j] + k0),
            (__attribute__((address_space(3))) void*)(AsB + (wv * 4 + j) * 1024),
            16, 0, 0);
    }
#pragma unroll
    for (int j = 0; j < 4; ++j)
      __builtin_amdgcn_global_load_lds(
          (const __attribute__((address_space(1))) void*)(bSrc[j] + k0),
          (__attribute__((address_space(3))) void*)(BsB + (wv * 4 + j) * 1024),
          16, 0, 0);
    __syncthreads();
#pragma unroll
    for (int kk = 0; kk < 2; ++kk) {
      bf16x8 af[4], bfr[4];
#pragma unroll
      for (int i = 0; i < 4; ++i) {
        const int ra = wr + i * 16 + lrow;
        if constexpr (AB16) {
          af[i] = *(const bf16x8*)(AsB + ra * 128 + ((((kk << 2) + kg) ^ (ra & 7)) << 4));
        } else {
          const char* pa = AsB + ra * 256 + ((kk * 128 + (kg << 5)) ^ ((ra & 7) << 5));
          af[i] = cvt_bf16x8(*(const f32x4*)pa, *(const f32x4*)(pa + 16));
        }
        const int rb = wc + i * 16 + lrow;
        bfr[i] = *(const bf16x8*)(BsB + rb * 128 + ((((kk << 2) + kg) ^ (rb & 7)) << 4));
      }
#pragma unroll
      for (int i = 0; i < 4; ++i)
#pragma unroll
        for (int j = 0; j < 4; ++j)
          acc[i][j] = __builtin_amdgcn_mfma_f32_16x16x32_bf16(af[i], bfr[j], acc[i][j], 0, 0, 0);
    }
    __syncthreads();
  }

  const size_t zoff = (SPLITZ > 1) ? (size_t)z * (size_t)M * (size_t)N : 0;
#pragma unroll
  for (int i = 0; i < 4; ++i) {
#pragma unroll
    for (int j = 0; j < 4; ++j) {
      const int col = bn * 256 + wc + j * 16 + lrow;
      if (col >= N) continue;
      const int row0 = bm * 128 + wr + i * 16 + kg * 4;
      float bv = 0.f;
      if (BIAS) bv = bias[col];
#pragma unroll
      for (int rr = 0; rr < 4; ++rr) {
        const int gr = row0 + rr;
        if (gr < M) {
          const float v = acc[i][j][rr] + bv;
          if constexpr (std::is_same<OutT, __half>::value)
            C[zoff + (size_t)gr * (size_t)N + col] = __float2half(v);
          else
            C[zoff + (size_t)gr * (size_t)N + col] = v;
        }
      }
    }
  }
}

// =======================================================================
// bgemm_film: gamma = ctxb@WgT+bg, beta = ctxb@WbT+bb, then
// hcb = bf16((1+gamma)*hx + beta). M=4096 N=512 K=512.
// =======================================================================
__global__ __launch_bounds__(512, 2) void bgemm_film(
    const ushort_t* __restrict__ A, const ushort_t* __restrict__ BG,
    const ushort_t* __restrict__ BB, const float* __restrict__ bg,
    const float* __restrict__ bb, const float* __restrict__ hx,
    ushort_t* __restrict__ hcb)
{
  constexpr int M = 4096, N = 512, K = 512;
  __shared__ __align__(16) char AsB[16384];
  __shared__ __align__(16) char BsB[65536];   // G:[0,32K) B:[32K,64K)
  const int tid = threadIdx.x, lane = tid & 63, wv = tid >> 6;

  const int nwg = gridDim.x;
  const int hw = blockIdx.x;
  const int q = nwg >> 3, r = nwg & 7;
  const int xcd = hw & 7, pos = hw >> 3;
  const int lid = (xcd < r ? xcd * (q + 1) : r * (q + 1) + (xcd - r) * q) + pos;
  const int bn = lid % 2;
  const int bm = lid / 2;

  const int wr = (wv >> 2) * 64;
  const int wc = (wv & 3) * 64;
  const int lrow = lane & 15, kg = lane >> 4;

  f32x4 accG[4][4], accB[4][4];
#pragma unroll
  for (int i = 0; i < 4; ++i)
#pragma unroll
    for (int j = 0; j < 4; ++j) {
      accG[i][j] = f32x4{0.f, 0.f, 0.f, 0.f};
      accB[i][j] = f32x4{0.f, 0.f, 0.f, 0.f};
    }

  const int r0 = lane >> 3;
  const int ce = ((lane & 7) ^ r0) << 3;
  const ushort_t* aSrc[2];
#pragma unroll
  for (int j = 0; j < 2; ++j) {
    const int row = wv * 16 + j * 8 + r0;
    aSrc[j] = A + (size_t)(bm * 128 + row) * (size_t)K + ce;
  }
  const ushort_t* gSrc[4];
  const ushort_t* bSrc[4];
#pragma unroll
  for (int j = 0; j < 4; ++j) {
    const int row = wv * 32 + j * 8 + r0;
    gSrc[j] = BG + (size_t)(bn * 256 + row) * (size_t)K + ce;
    bSrc[j] = BB + (size_t)(bn * 256 + row) * (size_t)K + ce;
  }

  for (int kb = 0; kb < K / 64; ++kb) {
    const int k0 = kb << 6;
#pragma unroll
    for (int j = 0; j < 2; ++j)
      __builtin_amdgcn_global_load_lds(
          (const __attribute__((address_space(1))) void*)(aSrc[j] + k0),
          (__attribute__((address_space(3))) void*)(AsB + (wv * 2 + j) * 1024),
          16, 0, 0);
#pragma unroll
    for (int j = 0; j < 4; ++j) {
      __builtin_amdgcn_global_load_lds(
          (const __attribute__((address_space(1))) void*)(gSrc[j] + k0),
          (__attribute__((address_space(3))) void*)(BsB + (wv * 4 + j) * 1024),
          16, 0, 0);
      __builtin_amdgcn_global_load_lds(
          (const __attribute__((address_space(1))) void*)(bSrc[j] + k0),
          (__attribute__((address_space(3))) void*)(BsB + 32768 + (wv * 4 + j) * 1024),
          16, 0, 0);
    }
    __syncthreads();
#pragma unroll
    for (int kk = 0; kk < 2; ++kk) {
      bf16x8 af[4], bfG[4], bfB[4];
#pragma unroll
      for (int i = 0; i < 4; ++i) {
        const int ra = wr + i * 16 + lrow;
        af[i] = *(const bf16x8*)(AsB + ra * 128 + ((((kk << 2) + kg) ^ (ra & 7)) << 4));
        const int rb = wc + i * 16 + lrow;
        const int bo = rb * 128 + ((((kk << 2) + kg) ^ (rb & 7)) << 4);
        bfG[i] = *(const bf16x8*)(BsB + bo);
        bfB[i] = *(const bf16x8*)(BsB + 32768 + bo);
      }
#pragma unroll
      for (int i = 0; i < 4; ++i)
#pragma unroll
        for (int j = 0; j < 4; ++j) {
          accG[i][j] = __builtin_amdgcn_mfma_f32_16x16x32_bf16(af[i], bfG[j], accG[i][j], 0, 0, 0);
          accB[i][j] = __builtin_amdgcn_mfma_f32_16x16x32_bf16(af[i], bfB[j], accB[i][j], 0, 0, 0);
        }
    }
    __syncthreads();
  }

#pragma unroll
  for (int i = 0; i < 4; ++i) {
#pragma unroll
    for (int j = 0; j < 4; ++j) {
      const int col = bn * 256 + wc + j * 16 + lrow;
      const float gvb = bg[col], bvb = bb[col];
      const int row0 = bm * 128 + wr + i * 16 + kg * 4;
#pragma unroll
      for (int rr = 0; rr < 4; ++rr) {
        const int gr = row0 + rr;
        const float gm = accG[i][j][rr] + gvb;
        const float bt = accB[i][j][rr] + bvb;
        const float h = hx[(size_t)gr * N + col];
        hcb[(size_t)gr * N + col] = rnd_bf16((1.f + gm) * h + bt);
      }
    }
  }
}

// ---------------- fp32 -> bf16 convert (8 elems/thread)
__global__ __launch_bounds__(256) void f2b(
    const float4* __restrict__ in, u32x4* __restrict__ out, int n8)
{
  const int i = blockIdx.x * 256 + threadIdx.x;
  if (i < n8) {
    const float4 a = in[2 * i], b = in[2 * i + 1];
    u32x4 o = { pack_bf16(a.x, a.y), pack_bf16(a.z, a.w),
                pack_bf16(b.x, b.y), pack_bf16(b.z, b.w) };
    out[i] = o;
  }
}

// ------- batched small-weight converts: blocks 0-127 W_ga, 128-255 W_gamma,
// 256-383 W_beta, 384-639 W_exp
__global__ __launch_bounds__(256) void f2b4(
    const float4* __restrict__ a, u32x4* __restrict__ oa,
    const float4* __restrict__ b, u32x4* __restrict__ ob,
    const float4* __restrict__ c, u32x4* __restrict__ oc,
    const float4* __restrict__ d, u32x4* __restrict__ od)
{
  const int blk = blockIdx.x;
  const float4* in;
  u32x4* out;
  int base;
  if (blk < 128)      { in = a; out = oa; base = 0; }
  else if (blk < 256) { in = b; out = ob; base = 128; }
  else if (blk < 384) { in = c; out = oc; base = 256; }
  else                { in = d; out = od; base = 384; }
  const int i = (blk - base) * 256 + threadIdx.x;
  const float4 x0 = in[2 * i], x1 = in[2 * i + 1];
  out[i] = u32x4{ pack_bf16(x0.x, x0.y), pack_bf16(x0.z, x0.w),
                  pack_bf16(x1.x, x1.y), pack_bf16(x1.z, x1.w) };
}

// ------- fused: sum 4 split-K partials + bias + LN + GELU + l2norm -> hx,hxb
__global__ __launch_bounds__(256) void gee_fuse_ln1(
    const float* __restrict__ P, const float* __restrict__ b_enc,
    const float* __restrict__ g1, const float* __restrict__ b1,
    float* __restrict__ hx, unsigned int* __restrict__ hxb)
{
  const int row = blockIdx.x, tid = threadIdx.x;
  __shared__ float red[16];
  const size_t MN = (size_t)4096 * 512;
  const size_t o2 = (size_t)row * 256 + tid;
  float2 v = ((const float2*)b_enc)[tid];
#pragma unroll
  for (int qq = 0; qq < 4; ++qq) {
    const float2 p = ((const float2*)P)[qq * (MN / 2) + o2];
    v.x += p.x; v.y += p.y;
  }
  float a = v.x + v.y;
  float b = v.x * v.x + v.y * v.y;
#pragma unroll
  for (int o = 32; o > 0; o >>= 1) { a += __shfl_xor(a, o); b += __shfl_xor(b, o); }
  const int lane = tid & 63, wvi = tid >> 6;
  if (lane == 0) { red[wvi] = a; red[8 + wvi] = b; }
  __syncthreads();
  const float mu  = (red[0] + red[1] + red[2] + red[3]) * (1.f / 512.f);
  const float ex2 = (red[8] + red[9] + red[10] + red[11]) * (1.f / 512.f);
  const float inv = rsqrtf(ex2 - mu * mu + 1e-5f);
  const float2 gg = ((const float2*)g1)[tid];
  const float2 bb = ((const float2*)b1)[tid];
  const float y0 = (v.x - mu) * inv * gg.x + bb.x;
  const float y1 = (v.y - mu) * inv * gg.y + bb.y;
  const float t0 = 0.5f * y0 * (1.f + erff(y0 * 0.70710678118654752f));
  const float t1 = 0.5f * y1 * (1.f + erff(y1 * 0.70710678118654752f));
  float ss = t0 * t0 + t1 * t1;
  __syncthreads();
#pragma unroll
  for (int o = 32; o > 0; o >>= 1) ss += __shfl_xor(ss, o);
  if (lane == 0) red[wvi] = ss;
  __syncthreads();
  const float sc = 1.f / fmaxf(sqrtf(red[0] + red[1] + red[2] + red[3]), 1e-12f);
  const float h0 = t0 * sc, h1 = t1 * sc;
  ((float2*)hx)[o2] = make_float2(h0, h1);
  hxb[o2] = pack_bf16(h0, h1);
}

// ---------------- row l2norm of raw e [20000,512] fp16 -> eb bf16
__global__ __launch_bounds__(256) void gee_l2rows(
    const __half2* __restrict__ ein, unsigned int* __restrict__ eb)
{
  const int row = blockIdx.x, tid = threadIdx.x;
  __shared__ float red[4];
  const __half2 h = ein[(size_t)row * 256 + tid];
  const float vx = __half2float(h.x), vy = __half2float(h.y);
  float ss = vx * vx + vy * vy;
#pragma unroll
  for (int o = 32; o > 0; o >>= 1) ss += __shfl_xor(ss, o);
  if ((tid & 63) == 0) red[tid >> 6] = ss;
  __syncthreads();
  const float sc = 1.f / fmaxf(sqrtf(red[0] + red[1] + red[2] + red[3]), 1e-12f);
  eb[(size_t)row * 256 + tid] = pack_bf16(vx * sc, vy * sc);
}

// -------- top-64 + softmax + fused ctx gather. Speculative compaction:
// scan 1 histograms AND compacts keys with byte >= SPEC (0xAD); verified
// against exact counts; falls back to exact scan 2 if speculation fails.
__global__ __launch_bounds__(256) void gee_topk_ctx(
    const __half* __restrict__ scores, const unsigned int* __restrict__ eb,
    unsigned int* __restrict__ ctxb)
{
  constexpr int G = 20000, GQ = G / 8, CAP = 2048, TCAP = 160;
  constexpr unsigned int SPEC = 0xADu;
  const int row = blockIdx.x, tid = threadIdx.x;
  const int lane = tid & 63, wv = tid >> 6;
  __shared__ int hist[4][256];
  __shared__ int cnt_ge[256];
  __shared__ int wtop[4];
  __shared__ unsigned int comp[CAP];
  __shared__ int whist[4][16];
  __shared__ int sel[64];
  __shared__ float swt[64];
  __shared__ int tie[TCAP];
  __shared__ int s_thr, s_above, s_cand, s_cnt, s_n1, s_n2;

  const u32x4* srow128 = (const u32x4*)((const ushort_t*)scores + (size_t)row * G);
  const ushort_t* srow16 = (const ushort_t*)srow128;

#pragma unroll
  for (int b = 0; b < 4; ++b) hist[b][tid] = 0;
  if (tid == 0) { s_cnt = 0; s_n1 = 0; s_n2 = 0; }
  __syncthreads();

  // ---- scan 1 (vectorized): histogram + speculative compaction
  for (int j0 = 0; j0 < GQ; j0 += 256) {
    const int j = j0 + tid;
    if (j < GQ) {
      const u32x4 pv = srow128[j];
#pragma unroll
      for (int c = 0; c < 4; ++c) {
        const unsigned int p = pv[c];
        const unsigned int f = (((p >> 15) & 0x10001u) * 0x7FFFu) + 0x80008000u;
        const unsigned int k2 = p ^ f;
        const unsigned int bl = (k2 >> 8) & 0xFFu, bh = k2 >> 24;
        atomicAdd(&hist[wv][bl], 1);
        atomicAdd(&hist[wv][bh], 1);
        if (bl >= SPEC) {
          const int pp = atomicAdd(&s_cnt, 1);
          if (pp < CAP) comp[pp] = ((k2 & 0xFFFFu) << 16) | (unsigned)(8 * j + 2 * c);
        }
        if (bh >= SPEC) {
          const int pp = atomicAdd(&s_cnt, 1);
          if (pp < CAP) comp[pp] = ((k2 >> 16) << 16) | (unsigned)(8 * j + 2 * c + 1);
        }
      }
    }
  }
  __syncthreads();
  cnt_ge[tid] = hist[0][tid] + hist[1][tid] + hist[2][tid] + hist[3][tid];
  __syncthreads();
  for (int off = 1; off < 256; off <<= 1) {
    const int add = (tid + off < 256) ? cnt_ge[tid + off] : 0;
    __syncthreads();
    cnt_ge[tid] += add;
    __syncthreads();
  }
  {
    const unsigned long long m = __ballot(cnt_ge[tid] >= 64);
    if (lane == 0) wtop[wv] = m ? (wv * 64 + 63 - __clzll(m)) : -1;
  }
  __syncthreads();
  if (tid == 0) {
    const int thrB = max(max(wtop[0], wtop[1]), max(wtop[2], wtop[3]));
    s_cand  = cnt_ge[thrB];
    s_above = (thrB == 255) ? 0 : cnt_ge[thrB + 1];
    s_thr   = thrB << 8;
  }
  __syncthreads();

  const unsigned int thrB = ((unsigned int)s_thr) >> 8;
  const int specCnt = cnt_ge[SPEC];
  const bool useSpec = (thrB >= SPEC) && (specCnt <= CAP);
  const bool useComp = useSpec || (s_cand <= CAP);

  // ---- scan 2 (only if speculation failed but candidates fit)
  if (!useSpec && useComp) {
    __syncthreads();
    if (tid == 0) s_cnt = 0;
    __syncthreads();
    for (int j0 = 0; j0 < GQ; j0 += 256) {
      const int j = j0 + tid;
      if (j < GQ) {
        const u32x4 pv = srow128[j];
#pragma unroll
        for (int c = 0; c < 4; ++c) {
          const unsigned int p = pv[c];
          const unsigned int f = (((p >> 15) & 0x10001u) * 0x7FFFu) + 0x80008000u;
          const unsigned int k2 = p ^ f;
          const unsigned int lo = k2 & 0xFFFFu, hi = k2 >> 16;
          if ((lo >> 8) >= thrB) {
            const int pp = atomicAdd(&s_cnt, 1);
            comp[pp] = (lo << 16) | (unsigned)(8 * j + 2 * c);
          }
          if ((hi >> 8) >= thrB) {
            const int pp = atomicAdd(&s_cnt, 1);
            comp[pp] = (hi << 16) | (unsigned)(8 * j + 2 * c + 1);
          }
        }
      }
    }
  }
  __syncthreads();
  const int Nloop = useComp ? min(s_cnt, CAP) : G;

  // ---- nibble passes: bits [7:4], [3:0]
  for (int pass = 2; pass < 4; ++pass) {
    const int shift = 12 - 4 * pass;
    const unsigned int thr = (unsigned int)s_thr;
    const unsigned int pfx = thr >> (shift + 4);
    int c[16];
#pragma unroll
    for (int b = 0; b < 16; ++b) c[b] = 0;
    for (int j0 = 0; j0 < Nloop; j0 += 256) {
      const int j = j0 + tid;
      const bool ok = j < Nloop;
      unsigned int key;
      if (useComp) {
        key = ok ? (comp[j] >> 16) : 0u;
      } else {
        const unsigned int raw = ok ? (unsigned int)srow16[j] : 0u;
        key = (raw & 0x8000u) ? (0xFFFFu & ~raw) : (raw | 0x8000u);
      }
      const unsigned int nb = (ok && (key >> (shift + 4)) == pfx) ? ((key >> shift) & 15u) : 0xFFu;
#pragma unroll
      for (int b = 0; b < 16; ++b) c[b] += __popcll(__ballot(nb == (unsigned)b));
    }
    if (lane == 0) {
#pragma unroll
      for (int b = 0; b < 16; ++b) whist[wv][b] = c[b];
    }
    __syncthreads();
    if (tid == 0) {
      int run = s_above;
      for (int vv = 15; vv >= 0; --vv) {
        const int c4 = whist[0][vv] + whist[1][vv] + whist[2][vv] + whist[3][vv];
        if (run + c4 >= 64) { s_thr |= vv << shift; break; }
        run += c4;
      }
      s_above = run;
    }
    __syncthreads();
  }

  // ---- selection (comp superset harmless: keys below thrB byte < kthr)
  const unsigned int kthr = (unsigned int)s_thr;
  for (int j0 = 0; j0 < Nloop; j0 += 256) {
    const int j = j0 + tid;
    if (j < Nloop) {
      unsigned int key, idx;
      if (useComp) {
        const unsigned int u = comp[j];
        key = u >> 16; idx = u & 0xFFFFu;
      } else {
        const unsigned int raw = (unsigned int)srow16[j];
        key = (raw & 0x8000u) ? (0xFFFFu & ~raw) : (raw | 0x8000u);
        idx = (unsigned)j;
      }
      if (key > kthr) {
        const int pp = atomicAdd(&s_n1, 1);
        sel[pp] = (int)idx;
      } else if (key == kthr) {
        const int pp = atomicAdd(&s_n2, 1);
        if (pp < TCAP) tie[pp] = (int)idx;
      }
    }
  }
  __syncthreads();
  if (tid == 0) {
    const int n1 = s_n1;
    const int n2 = min(s_n2, TCAP);
    const int need = 64 - n1;
    for (int rr = 0; rr < need; ++rr) {       // smallest indices (top_k tie-break)
      int best = 1 << 30, bj = 0;
      for (int j = 0; j < n2; ++j)
        if (tie[j] < best) { best = tie[j]; bj = j; }
      sel[n1 + rr] = best;
      tie[bj] = 1 << 30;
    }
  }
  __syncthreads();
  if (tid < 64) {
    const int idx = sel[tid];
    const float sv = __half2float(scores[(size_t)row * G + idx]) * 10.0f;  // 1/T
    float m = sv;
#pragma unroll
    for (int o = 32; o > 0; o >>= 1) m = fmaxf(m, __shfl_xor(m, o));
    const float w = __expf(sv - m);
    float d = w;
#pragma unroll
    for (int o = 32; o > 0; o >>= 1) d += __shfl_xor(d, o);
    swt[tid] = w / d;
  }
  __syncthreads();
  float a0 = 0.f, a1 = 0.f;
#pragma unroll 4
  for (int k = 0; k < 64; ++k) {
    const unsigned int pk = eb[(size_t)sel[k] * 256 + tid];
    const float wk = swt[k];
    a0 += wk * __uint_as_float(pk << 16);
    a1 += wk * __uint_as_float(pk & 0xFFFF0000u);
  }
  ctxb[(size_t)row * 256 + tid] = pack_bf16(a0, a1);
}

// ---------------- LN2 + exact GELU -> out [4096,1024]
__global__ __launch_bounds__(256) void gee_ln2(
    const float* __restrict__ h2, const float* __restrict__ g2,
    const float* __restrict__ b2, float* __restrict__ out)
{
  const int row = blockIdx.x, tid = threadIdx.x;
  __shared__ float red[16];
  float v[4];
  float a = 0.f, b = 0.f;
#pragma unroll
  for (int e = 0; e < 4; ++e) {
    v[e] = h2[(size_t)row * 1024 + tid + e * 256];
    a += v[e]; b += v[e] * v[e];
  }
#pragma unroll
  for (int o = 32; o > 0; o >>= 1) { a += __shfl_xor(a, o); b += __shfl_xor(b, o); }
  const int lane = tid & 63, wvi = tid >> 6;
  if (lane == 0) { red[wvi] = a; red[8 + wvi] = b; }
  __syncthreads();
  const float mu  = (red[0] + red[1] + red[2] + red[3]) * (1.f / 1024.f);
  const float ex2 = (red[8] + red[9] + red[10] + red[11]) * (1.f / 1024.f);
  const float inv = rsqrtf(ex2 - mu * mu + 1e-5f);
#pragma unroll
  for (int e = 0; e < 4; ++e) {
    const int c = tid + e * 256;
    const float y = (v[e] - mu) * inv * g2[c] + b2[c];
    out[(size_t)row * 1024 + c] = 0.5f * y * (1.f + erff(y * 0.70710678118654752f));
  }
}

extern "C" void kernel_launch(void* const* d_in, const int* in_sizes, int n_in,
                              void* d_out, int out_size, void* d_ws, size_t ws_size,
                              hipStream_t stream)
{
  const float* x       = (const float*)d_in[0];
  const float* g       = (const float*)d_in[1];
  const float* W_enc   = (const float*)d_in[2];
  const float* b_enc   = (const float*)d_in[3];
  const float* ln1_g   = (const float*)d_in[4];
  const float* ln1_b   = (const float*)d_in[5];
  const float* W_ga    = (const float*)d_in[6];
  const float* W_gamma = (const float*)d_in[7];
  const float* b_gamma = (const float*)d_in[8];
  const float* W_beta  = (const float*)d_in[9];
  const float* b_beta  = (const float*)d_in[10];
  const float* W_exp   = (const float*)d_in[11];
  const float* b_exp   = (const float*)d_in[12];
  const float* ln2_g   = (const float*)d_in[13];
  const float* ln2_b   = (const float*)d_in[14];
  float* out = (float*)d_out;

  char* ws = (char*)d_ws;
  constexpr size_t OFF_SCORES = 0;            // 163,840,000 (t5-t6)
  constexpr size_t OFF_H2     = 0;            // 16,777,216 (t10+, scores dead)
  constexpr size_t OFF_PART   = 163840000;    // 33,554,432
  constexpr size_t OFF_WENCB  = 197394432;    // 20,480,000 (t0-t1) -> e (t3-t4)
  constexpr size_t OFF_E      = 197394432;    // alias
  constexpr size_t OFF_EB     = 217874432;    // 20,480,000
  constexpr size_t OFF_HX     = 238354432;    // 8,388,608
  constexpr size_t OFF_HXB    = 246743040;    // 4,194,304
  constexpr size_t OFF_CTXB   = 250937344;    // 4,194,304
  constexpr size_t OFF_HCB    = 255131648;    // 4,194,304
  constexpr size_t OFF_WGAB   = 259325952;    // 524,288
  constexpr size_t OFF_WGMB   = 259850240;    // 524,288
  constexpr size_t OFF_WBTB   = 260374528;    // 524,288
  constexpr size_t OFF_WEXB   = 260898816;    // 1,048,576 -> total 261,947,392

  __half*       scores = (__half*)(ws + OFF_SCORES);
  float*        h2     = (float*)(ws + OFF_H2);
  float*        part   = (float*)(ws + OFF_PART);
  ushort_t*     wencb  = (ushort_t*)(ws + OFF_WENCB);
  __half*       e      = (__half*)(ws + OFF_E);
  unsigned int* eb     = (unsigned int*)(ws + OFF_EB);
  float*        hx     = (float*)(ws + OFF_HX);
  unsigned int* hxb    = (unsigned int*)(ws + OFF_HXB);
  unsigned int* ctxb   = (unsigned int*)(ws + OFF_CTXB);
  ushort_t*     hcb    = (ushort_t*)(ws + OFF_HCB);
  ushort_t*     wgab   = (ushort_t*)(ws + OFF_WGAB);
  ushort_t*     wgmb   = (ushort_t*)(ws + OFF_WGMB);
  ushort_t*     wbtb   = (ushort_t*)(ws + OFF_WBTB);
  ushort_t*     wexb   = (ushort_t*)(ws + OFF_WEXB);

  // 0) weight converts fp32 -> bf16 (W_enc big; 4 small weights batched)
  f2b<<<5000, 256, 0, stream>>>((const float4*)W_enc, (u32x4*)wencb, 1280000);
  f2b4<<<640, 256, 0, stream>>>(
      (const float4*)W_ga,    (u32x4*)wgab,
      (const float4*)W_gamma, (u32x4*)wgmb,
      (const float4*)W_beta,  (u32x4*)wbtb,
      (const float4*)W_exp,   (u32x4*)wexb);

  // 1) split-K=4 partials of x(fp32) @ wencb^T -> part[4][4096][512]
  bgemmA32<4, true, float><<<256, 512, 0, stream>>>(
      x, wencb, part, 4096, 512, 20000, 2, 32);
  // 2) h_x = l2norm(gelu(LN1(sum partials + b_enc)))
  gee_fuse_ln1<<<4096, 256, 0, stream>>>(part, b_enc, ln1_g, ln1_b, hx, hxb);
  // 3) e_raw = g @ W_ga^T  [20000][512] fp16 (single-buf, 2/CU; r13 lesson)
  bgemm<float, 1, false, __half><<<314, 512, 0, stream>>>(
      g, wgab, nullptr, e, 20000, 512, 512, 2, 157);
  // 4) eb = l2norm rows (bf16)
  gee_l2rows<<<20000, 256, 0, stream>>>((const __half2*)e, eb);
  // 5) scores = hxb @ eb^T  (fp16 out)
  bgemm256<1, __half><<<1264, 512, 0, stream>>>(
      (const ushort_t*)hxb, (const ushort_t*)eb, scores, 4096, 20000, 512, 79, 16);
  // 6+7) top-64 + softmax + fused ctx gather -> ctxb
  gee_topk_ctx<<<4096, 256, 0, stream>>>(scores, eb, ctxb);
  // 8+9) FiLM: gamma,beta GEMMs + (1+g)*hx+b fused -> hcb bf16
  bgemm_film<<<64, 512, 0, stream>>>(
      (const ushort_t*)ctxb, wgmb, wbtb, b_gamma, b_beta, hx, hcb);
  // 10) h2 = h_cell @ W_exp^T + b_exp  (bf16-A)
  bgemm<ushort_t, 1, true, float><<<128, 512, 0, stream>>>(
      hcb, wexb, b_exp, h2, 4096, 1024, 512, 4, 32);
  // 11) out = gelu(LN2(h2))
  gee_ln2<<<4096, 256, 0, stream>>>(h2, ln2_g, ln2_b, out);
}